// Round 8
// baseline (465.543 us; speedup 1.0000x reference)
//
#include <hip/hip_runtime.h>
#include <cmath>

#define BATCH 2
#define CIN 3
#define HH 96
#define WW 96
#define NSP (HH*WW)      // 9216
#define CHN 64
#define C8 8
#define NBLK 5

#define PW 98            // padded width/height (3x3 convs)
#define PN (PW*PW)       // 9604 padded spatial
#define GUARD 128        // guard rows (spatial) each side of FBI buffers
#define FBST ((PN + 2*GUARD)*128)  // shorts per batch in FBI (hi|lo interleaved)

#define PW2 104          // padded width for 9x9 conv_out input
#define PN2 (PW2*PW2)    // 10816

#define NRB (NSP/32)     // 288 row-blocks in attention
#define NCHK 144         // 64-col j-chunks (9216/64)
#define NQTR 6           // j split across 6 blocks (24 chunks each, 6/wave)

#define KPAD 16          // Kinf padded stride (floats) -> 1 entry per 64B line

#define LOG2E 1.4426950408889634f
#define BOOST 100.0f     // exponent boost: p' = 2^(e-M+BOOST), overflow-safe

typedef __attribute__((ext_vector_type(8))) short bf16x8;
typedef __attribute__((ext_vector_type(4))) float f32x4;

static __device__ __forceinline__ short f2b(float f) {
    union { float f; unsigned u; } v; v.f = f;
    unsigned r = (v.u + 0x7FFFu + ((v.u >> 16) & 1u)) >> 16;
    return (short)r;
}
static __device__ __forceinline__ float b2f(short s) {
    union { unsigned u; float f; } v; v.u = ((unsigned)(unsigned short)s) << 16;
    return v.f;
}
static __device__ __forceinline__ void split2(float v, short& hi, short& lo) {
    hi = f2b(v);
    lo = f2b(v - b2f(hi));
}

// ---------------------------------------------------------------------------
// merged weight prep (single launch replaces 4 tiny ones).
__global__ __launch_bounds__(256) void k_prep_all(
        const float* __restrict__ rw1, const float* __restrict__ rw2,
        short* __restrict__ Whi, short* __restrict__ Wlo,
        const float* __restrict__ wq, const float* __restrict__ wk,
        const float* __restrict__ wv,
        short* __restrict__ Wqh, short* __restrict__ Wql,
        const float* __restrict__ w_out, float* __restrict__ Wo,
        const float* __restrict__ w_in, float* __restrict__ Win) {
    int idx = blockIdx.x * 256 + threadIdx.x;
    const int TOT_A = NBLK*2*9*CHN*CHN;   // 368640
    const int TOT_B = 80*CHN;             //   5120
    const int TOT_C = 81*CIN*CHN;         //  15552
    if (idx < TOT_A) {
        int ci  = idx & 63;
        int co  = (idx >> 6) & 63;
        int kyx = (idx >> 12) % 9;
        int conv = idx / (9*CHN*CHN);
        int blk = conv >> 1, s = conv & 1;
        const float* src = s ? rw2 : rw1;
        float v = src[(((size_t)(blk*CHN + co))*CHN + ci)*9 + kyx];
        short h, l; split2(v, h, l);
        Whi[idx] = h; Wlo[idx] = l;
        return;
    }
    idx -= TOT_A;
    if (idx < TOT_B) {
        int ci = idx & 63, co = idx >> 6;
        float v;
        if (co < 8)       v = wq[co*CHN + ci];
        else if (co < 16) v = wk[(co-8)*CHN + ci];
        else              v = wv[(co-16)*CHN + ci];
        short h, l; split2(v, h, l);
        Wqh[idx] = h; Wql[idx] = l;
        return;
    }
    idx -= TOT_B;
    if (idx < TOT_C) {
        int ci = idx & 63;
        int co = (idx >> 6) % 3;
        int kyx = idx / 192;
        Wo[idx] = w_out[((size_t)(co*CHN + ci))*81 + kyx];
        return;
    }
    idx -= TOT_C;
    if (idx < 243*CHN) {
        int co = idx & 63;
        int k  = idx >> 6;          // 0..242
        int ci = k / 81, kk = k % 81;
        Win[idx] = w_in[((size_t)(co*CIN + ci))*81 + kk];
    }
}

// ---------------------------------------------------------------------------
// conv 9x9 (3 -> 64), pad 4, + PReLU. x window staged once in LDS.
// XCD-swizzled (y-slab per XCD, matches conv3's mapping).
__global__ __launch_bounds__(256) void k_conv_in(const float* __restrict__ x,
        const float* __restrict__ Win, const float* __restrict__ bias,
        const float* __restrict__ a, float* __restrict__ FR,
        short* __restrict__ FBI) {
    __shared__ float xw[3*9*40];     // [ci][ky][c], c = xs-(x0-4), 4320 B
    int t = threadIdx.x;
    int blk = blockIdx.x;
    int xcd = blk & 7;
    int l   = blk >> 3;              // 0..143 = b(2) x y%12(12) x s(6)
    int b   = l / 72;
    int r   = l % 72;
    int y   = xcd*12 + r/6;
    int s   = r % 6;                 // xc*2 + coh
    int xc  = s >> 1;
    int coh = s & 1;
    int x0 = xc*32;
    int px  = t & 31;
    int cog = t >> 5;                // 8 groups x 4 co (within this half)

    // ---- stage x window: rows y-4..y+4, cols x0-4..x0+35, 3 ci ----
    #pragma unroll
    for (int u = 0; u < 5; ++u) {
        int idx = u*256 + t;
        if (idx < 1080) {
            int ci = idx / 360;
            int rr = idx - ci*360;
            int ky = rr / 40;
            int c  = rr - ky*40;
            int yy = y + ky - 4;
            int xs = x0 + c - 4;
            float v = 0.f;
            if (yy >= 0 && yy < 96 && xs >= 0 && xs < 96)
                v = x[((size_t)(b*CIN + ci))*NSP + yy*96 + xs];
            xw[idx] = v;
        }
    }
    __syncthreads();

    int cbase = coh*32 + cog*4;
    float acc[4];
    #pragma unroll
    for (int rr = 0; rr < 4; ++rr) acc[rr] = bias[cbase + rr];

    #pragma unroll 1
    for (int ci = 0; ci < CIN; ++ci) {
        #pragma unroll 1
        for (int ky = 0; ky < 9; ++ky) {
            const float* xrow = xw + (ci*9 + ky)*40 + px;
            const float* wrow = Win + (size_t)(ci*81 + ky*9)*64 + cbase;
            float xv[9];
            #pragma unroll
            for (int kx = 0; kx < 9; ++kx) xv[kx] = xrow[kx];
            #pragma unroll
            for (int kx = 0; kx < 9; ++kx) {
                float4 wv = *(const float4*)(wrow + kx*64);
                acc[0] = fmaf(xv[kx], wv.x, acc[0]);
                acc[1] = fmaf(xv[kx], wv.y, acc[1]);
                acc[2] = fmaf(xv[kx], wv.z, acc[2]);
                acc[3] = fmaf(xv[kx], wv.w, acc[3]);
            }
        }
    }
    float sl = a[0];
    #pragma unroll
    for (int rr = 0; rr < 4; ++rr) {
        float v = acc[rr];
        acc[rr] = v >= 0.f ? v : sl*v;
    }
    int np = (y + 1)*PW + x0 + px + 1;
    float* fr = FR + ((size_t)b*PN + np)*CHN + cbase;
    *(float4*)fr = make_float4(acc[0], acc[1], acc[2], acc[3]);
    union { short ss[4]; short4 v4; } h4, l4;
    #pragma unroll
    for (int rr = 0; rr < 4; ++rr) split2(acc[rr], h4.ss[rr], l4.ss[rr]);
    short* fo = FBI + (size_t)b*FBST + (size_t)np*128 + cbase;
    *(short4*)fo        = h4.v4;
    *(short4*)(fo + 64) = l4.v4;
}

// ---------------------------------------------------------------------------
// 3x3 conv 64->64, implicit GEMM, split-bf16 3-MFMA, XCD-swizzled
// (y-slab per XCD -> producer/consumer stay in the same L2).
__global__ __launch_bounds__(256, 4) void k_conv3_mfma(
        const short* __restrict__ FBin,
        const short* __restrict__ Whi, const short* __restrict__ Wlo,
        const float* __restrict__ bias, const float* __restrict__ slope_p,
        float* __restrict__ FR, short* __restrict__ FBout, int mode) {
    __shared__ short xs[3*18*128];   // 13,824 B
    char* xb = (char*)xs;
    int t = threadIdx.x;
    int w = t >> 6, lane = t & 63;
    int q = lane >> 4, n16 = lane & 15;
    int blk = blockIdx.x;
    int xcd = blk & 7;
    int l   = blk >> 3;              // 0..143 = b(2) x y%12(12) x xchunk(6)
    int b   = l / 72;
    int rem = l % 72;
    int y   = xcd*12 + rem/6;
    int x0  = (rem % 6)*16;

    const short* fbB = FBin + (size_t)b*FBST;

    // ---- stage: 864 16-B granules, swizzled into LDS ----
    #pragma unroll
    for (int k = 0; k < 4; ++k) {
        int u = k*256 + t;
        if (u < 864) {
            int px_lin = u >> 4, G = u & 15;
            int r = px_lin / 18, p = px_lin - r*18;
            const float4 src = *(const float4*)(fbB
                + ((size_t)((y + r)*PW + x0 + p))*128 + G*8);
            *(float4*)(xb + (px_lin << 8) + ((G ^ (px_lin & 15)) << 4)) = src;
        }
    }
    __syncthreads();

    // ---- compute: wave = 16 px x 16 co (ct = w) ----
    int ct = w;
    f32x4 acc = {0,0,0,0};

    #pragma unroll
    for (int dy = 0; dy < 3; ++dy) {
        #pragma unroll
        for (int dx = 0; dx < 3; ++dx) {
            int kyx = dy*3 + dx;
            int px_lin = dy*18 + n16 + dx;
            int pbase = px_lin << 8;
            int sw = px_lin & 15;
            const short* wp_h = Whi + (size_t)kyx*CHN*CHN;
            const short* wp_l = Wlo + (size_t)kyx*CHN*CHN;
            #pragma unroll
            for (int cih = 0; cih < 2; ++cih) {
                int Gh = cih*4 + q;
                int Gl = 8 + cih*4 + q;
                bf16x8 bhi = *(const bf16x8*)(xb + pbase + ((Gh ^ sw) << 4));
                bf16x8 blo = *(const bf16x8*)(xb + pbase + ((Gl ^ sw) << 4));
                int aoff = (ct*16 + n16)*CHN + cih*32 + q*8;
                bf16x8 ahi = *(const bf16x8*)(wp_h + aoff);
                bf16x8 alo = *(const bf16x8*)(wp_l + aoff);
                acc = __builtin_amdgcn_mfma_f32_16x16x32_bf16(ahi, bhi, acc, 0, 0, 0);
                acc = __builtin_amdgcn_mfma_f32_16x16x32_bf16(ahi, blo, acc, 0, 0, 0);
                acc = __builtin_amdgcn_mfma_f32_16x16x32_bf16(alo, bhi, acc, 0, 0, 0);
            }
        }
    }

    // ---- epilogue: all outputs interior, vectorized stores ----
    int nb = (y + 1)*PW + x0 + 1 + n16;
    float sl = slope_p[0];
    short* fbo = FBout + (size_t)b*FBST + (size_t)nb*128;
    int co0 = ct*16 + q*4;
    float v[4];
    #pragma unroll
    for (int r = 0; r < 4; ++r) v[r] = acc[r] + bias[co0 + r];
    if (mode == 0) {
        #pragma unroll
        for (int r = 0; r < 4; ++r) v[r] = v[r] >= 0.f ? v[r] : sl*v[r];
    } else {
        float* fr = FR + ((size_t)b*PN + nb)*CHN + co0;
        float4 f = *(const float4*)fr;
        v[0] += f.x; v[1] += f.y; v[2] += f.z; v[3] += f.w;
        *(float4*)fr = make_float4(v[0], v[1], v[2], v[3]);
    }
    union { short s[4]; short4 v4; } h4, l4;
    #pragma unroll
    for (int r = 0; r < 4; ++r) split2(v[r], h4.s[r], l4.s[r]);
    *(short4*)(fbo + co0)      = h4.v4;
    *(short4*)(fbo + 64 + co0) = l4.v4;
}

// ---------------------------------------------------------------------------
// qkv projection as 1x1-conv implicit GEMM (80 outputs = 8 q + 8 k + 64 v).
// Blocks aligned to N-SPACE (n = chunk*64 + w*16 + n16, all valid): the old
// padded-nb alignment made every V fragment-store a 64-lane 2B scatter;
// n-alignment makes jin wave-local so V stores coalesce into 16B segments
// (8 lanes x 2B contiguous), and the border bounds-check disappears.
__global__ __launch_bounds__(256) void k_qkv_mfma(
        const short* __restrict__ FBin,
        const short* __restrict__ Wh, const short* __restrict__ Wl,
        const float* __restrict__ bq, const float* __restrict__ bk,
        const float* __restrict__ bv,
        short* __restrict__ Qb, short* __restrict__ Kb, short* __restrict__ Vb,
        float* __restrict__ Kinf) {
    __shared__ float kls[4][8];
    int t = threadIdx.x;
    int w = t >> 6, lane = t & 63;
    int q = lane >> 4, n16 = lane & 15;
    int blk = blockIdx.x;
    int b = blk / NCHK, chunk = blk % NCHK;
    int n  = chunk*64 + w*16 + n16;          // 0..9215, always valid
    int iy = n / WW, ix = n - iy*WW;
    int nb = (iy + 1)*PW + ix + 1;

    const short* fb = FBin + (size_t)b*FBST;
    f32x4 acc[5] = {{0,0,0,0},{0,0,0,0},{0,0,0,0},{0,0,0,0},{0,0,0,0}};

    int nbase = nb*128;
    #pragma unroll
    for (int cih = 0; cih < 2; ++cih) {
        bf16x8 bhi = *(const bf16x8*)(fb + nbase + cih*32 + q*8);
        bf16x8 blo = *(const bf16x8*)(fb + nbase + 64 + cih*32 + q*8);
        #pragma unroll
        for (int ct = 0; ct < 5; ++ct) {
            int aoff = (ct*16 + n16)*CHN + cih*32 + q*8;
            bf16x8 ahi = *(const bf16x8*)(Wh + aoff);
            bf16x8 alo = *(const bf16x8*)(Wl + aoff);
            acc[ct] = __builtin_amdgcn_mfma_f32_16x16x32_bf16(ahi, bhi, acc[ct], 0, 0, 0);
            acc[ct] = __builtin_amdgcn_mfma_f32_16x16x32_bf16(ahi, blo, acc[ct], 0, 0, 0);
            acc[ct] = __builtin_amdgcn_mfma_f32_16x16x32_bf16(alo, bhi, acc[ct], 0, 0, 0);
        }
    }

    int jin = w*16 + n16;                    // j within chunk, wave-local
    float kabs[4] = {0.f, 0.f, 0.f, 0.f};
    union { short s[4]; short4 v4; } pk;
    if (q < 2) {
        #pragma unroll
        for (int r = 0; r < 4; ++r)
            pk.s[r] = f2b((acc[0][r] + bq[q*4 + r]) * LOG2E);
        *(short4*)(Qb + ((size_t)b*NSP + n)*8 + q*4) = pk.v4;
    } else {
        // K fragment coords (inverse of attn's jrow mapping)
        int ttk  = ((jin >> 5) << 1) | ((jin >> 2) & 1);
        int n16k = (((jin >> 3) & 3) << 2) | (jin & 3);
        size_t kbase = (((size_t)(b*NCHK + chunk)*4 + ttk)*16 + n16k)*8;
        #pragma unroll
        for (int r = 0; r < 4; ++r) {
            float kv = acc[0][r] + bk[(q - 2)*4 + r];
            kabs[r] = fabsf(kv) * 1.01f;
            pk.s[r] = f2b(kv);
        }
        *(short4*)(Kb + kbase + (q - 2)*4) = pk.v4;
    }
    // V fragment coords (j = ks*32 + quad*8 + e within chunk)
    int ksv = jin >> 5, qv = (jin >> 3) & 3, ev = jin & 7;
    size_t vbase = ((size_t)(b*NCHK + chunk)*2 + ksv)*2048 + qv*128 + ev;
    #pragma unroll
    for (int ct = 1; ct < 5; ++ct) {
        #pragma unroll
        for (int r = 0; r < 4; ++r) {
            int co = ct*16 + q*4 + r;
            Vb[vbase + (size_t)(ct - 1)*512 + (q*4 + r)*8] =
                f2b(acc[ct][r] + bv[co - 16]);
        }
    }
    #pragma unroll
    for (int r = 0; r < 4; ++r) {
        #pragma unroll
        for (int off = 1; off < 16; off <<= 1)
            kabs[r] = fmaxf(kabs[r], __shfl_xor(kabs[r], off));
    }
    if (q >= 2 && n16 == 0) {
        #pragma unroll
        for (int r = 0; r < 4; ++r)
            kls[w][(q - 2)*4 + r] = kabs[r];
    }
    __syncthreads();
    if (t < 8) {
        float m = fmaxf(fmaxf(kls[0][t], kls[1][t]),
                        fmaxf(kls[2][t], kls[3][t]));
        atomicMax((int*)&Kinf[t*KPAD], __float_as_int(m));
    }
}

// ---------------------------------------------------------------------------
// chunk buffer for attention (single-buffered: TLP beats ILP here — both
// the full dbuf (r2) and K-prefetch (r6) variants lost to occupancy).
struct CB { bf16x8 kf[4]; bf16x8 vf[8]; };

static __device__ __forceinline__ void attn_load(CB& cb,
        const short* __restrict__ KpJ, const short* __restrict__ VpJ,
        int n16, int lane) {
    #pragma unroll
    for (int tt = 0; tt < 4; ++tt)
        cb.kf[tt] = *(const bf16x8*)(KpJ + tt*128 + n16*8);
    #pragma unroll
    for (int ks = 0; ks < 2; ++ks)
        #pragma unroll
        for (int ct = 0; ct < 4; ++ct)
            cb.vf[ks*4 + ct] = *(const bf16x8*)(VpJ + (ks*4 + ct)*512 + lane*8);
}

static __device__ __forceinline__ void attn_compute(const CB& cb,
        const bf16x8 (&qf)[2], const f32x4 (&ci)[2],
        f32x4 (&accO)[2][4], float (&lp)[2]) {
    union PB { int di[8]; bf16x8 v8[2]; };
    PB pb[2];
    #pragma unroll
    for (int rg = 0; rg < 2; ++rg) {
        f32x4 e[4];
        #pragma unroll
        for (int tt = 0; tt < 4; ++tt)
            e[tt] = __builtin_amdgcn_mfma_f32_16x16x32_bf16(
                cb.kf[tt], qf[rg], ci[rg], 0, 0, 0);
        float st[4];
        #pragma unroll
        for (int tt = 0; tt < 4; ++tt) {
            #pragma unroll
            for (int r = 0; r < 4; ++r)
                e[tt][r] = __builtin_amdgcn_exp2f(e[tt][r]);
            st[tt] = (e[tt][0] + e[tt][1]) + (e[tt][2] + e[tt][3]);
        }
        lp[rg] += (st[0] + st[1]) + (st[2] + st[3]);
        // pack P to bf16 fragments eagerly (frees the 16 f32 e regs)
        #pragma unroll
        for (int tt = 0; tt < 4; ++tt) {
            pb[rg].di[tt*2]   = __builtin_amdgcn_perm(__float_as_uint(e[tt][1]),
                                             __float_as_uint(e[tt][0]), 0x07060302u);
            pb[rg].di[tt*2+1] = __builtin_amdgcn_perm(__float_as_uint(e[tt][3]),
                                             __float_as_uint(e[tt][2]), 0x07060302u);
        }
    }
    #pragma unroll
    for (int ks = 0; ks < 2; ++ks)
        #pragma unroll
        for (int rg = 0; rg < 2; ++rg)
            #pragma unroll
            for (int ct = 0; ct < 4; ++ct)
                accO[rg][ct] = __builtin_amdgcn_mfma_f32_16x16x32_bf16(
                    pb[rg].v8[ks], cb.vf[ks*4 + ct], accO[rg][ct], 0, 0, 0);
}

// MFMA flash attention, bound-based softmax, j split across 6 blocks
// (grid 3456 = 13.5 blocks/CU; was 9 at NQTR=4 — occupancy measured 25%
// with VALUBusy 61%, i.e. work-starved per CU, so more blocks = more
// resident waves = higher VALU saturation). 6 chunks per wave.
__global__ __launch_bounds__(256) void k_attn_mfma(
        const short* __restrict__ Qb, const short* __restrict__ Kb,
        const short* __restrict__ Vb, const float* __restrict__ Kinf_p,
        float* __restrict__ Opg, float* __restrict__ lg) {
    __shared__ float Opart[4][16][68];
    __shared__ float lsh[4][2][16];

    int blk = blockIdx.x;
    int b    = blk / (NRB*NQTR);
    int rem  = blk % (NRB*NQTR);
    int rb   = rem / NQTR;
    int qtr  = rem % NQTR;
    int i0 = rb*32;
    int t = threadIdx.x;
    int w = t >> 6;
    int lane = t & 63;
    int quad = lane >> 4, n16 = lane & 15;

    const short* Qp = Qb + ((size_t)b*NSP)*8;
    const short* Kp = Kb + ((size_t)b*NSP)*8;
    const short* Vp = Vb + ((size_t)b*CHN)*NSP;

    bf16x8 qf[2];
    float Mi[2];
    #pragma unroll
    for (int rg = 0; rg < 2; ++rg) {
        bf16x8 z = {0,0,0,0,0,0,0,0};
        qf[rg] = z;
        if (quad == 0)
            qf[rg] = *(const bf16x8*)(Qp + (size_t)(i0 + rg*16 + n16)*8);
        float s1 = 0.f;
        #pragma unroll
        for (int c = 0; c < 8; ++c)
            s1 += fabsf(b2f(qf[rg][c])) * Kinf_p[c*KPAD];
        float Mv = s1 + 1.0f - BOOST;
        Mi[rg] = __shfl(Mv, n16);
    }

    f32x4 accO[2][4] = {{{0,0,0,0},{0,0,0,0},{0,0,0,0},{0,0,0,0}},
                        {{0,0,0,0},{0,0,0,0},{0,0,0,0},{0,0,0,0}}};
    float lp[2] = {0.f, 0.f};
    f32x4 ci[2];
    #pragma unroll
    for (int rg = 0; rg < 2; ++rg) {
        ci[rg][0] = -Mi[rg]; ci[rg][1] = -Mi[rg];
        ci[rg][2] = -Mi[rg]; ci[rg][3] = -Mi[rg];
    }

    // wave w covers 6 chunks of 64 j within its sixth
    int Jb = qtr*24 + w*6;
    const short* KpJ = Kp + (size_t)Jb*512;
    const short* VpJ = Vp + (size_t)Jb*4096;

    #pragma unroll 1
    for (int jc = 0; jc < 6; ++jc) {
        CB cb;
        attn_load(cb, KpJ, VpJ, n16, lane);
        attn_compute(cb, qf, ci, accO, lp);
        KpJ += 512;
        VpJ += 4096;
    }

    // ---- epilogue: cross-wave reduce, rg-looped to halve LDS ----
    #pragma unroll
    for (int rg = 0; rg < 2; ++rg) {
        float l = lp[rg];
        l += __shfl_xor(l, 16);
        l += __shfl_xor(l, 32);
        if (quad == 0) lsh[w][rg][n16] = l;
    }

    size_t obase = (((size_t)(b*NRB + rb))*NQTR + qtr)*2048;
    int row16 = t >> 4;          // 0..15
    int c0 = (t & 15)*4;
    #pragma unroll
    for (int rg = 0; rg < 2; ++rg) {
        if (rg) __syncthreads();
        #pragma unroll
        for (int ct = 0; ct < 4; ++ct)
            #pragma unroll
            for (int r = 0; r < 4; ++r)
                Opart[w][quad*4 + r][ct*16 + n16] = accO[rg][ct][r];
        __syncthreads();
        #pragma unroll
        for (int cc = 0; cc < 4; ++cc) {
            int c = c0 + cc;
            Opg[obase + (size_t)(rg*16 + row16)*64 + c] =
                Opart[0][row16][c] + Opart[1][row16][c]
              + Opart[2][row16][c] + Opart[3][row16][c];
        }
    }
    if (t < 32) {
        int rgl = t >> 4, ii = t & 15;
        lg[(((size_t)(b*NRB + rb))*NQTR + qtr)*32 + t] =
            lsh[0][rgl][ii] + lsh[1][rgl][ii]
          + lsh[2][rgl][ii] + lsh[3][rgl][ii];
    }
}

// ---------------------------------------------------------------------------
// attention finalize: merge 6 j-sixths, normalize, add residual, write AT.
__global__ __launch_bounds__(256) void k_attn_fin(
        const float* __restrict__ Opg, const float* __restrict__ lg,
        const float* __restrict__ FR, const float* __restrict__ gamma_p,
        float* __restrict__ AT) {
    int blk = blockIdx.x;            // b*NRB + rb
    int b = blk / NRB, rb = blk % NRB;
    int t = threadIdx.x;
    int row = t >> 3;
    int c0 = (t & 7)*8;
    float g = gamma_p[0];
    size_t ob = ((size_t)blk*NQTR)*2048 + (size_t)row*64;
    float l = 0.f;
    #pragma unroll
    for (int k = 0; k < NQTR; ++k)
        l += lg[((size_t)blk*NQTR + k)*32 + row];
    float inv = g / fmaxf(l, 1e-35f);
    int gi = rb*32 + row;
    int iy = gi / WW, ix = gi - iy*WW;
    size_t frb = ((size_t)b*PN + (iy + 1)*PW + ix + 1)*CHN;
    size_t atb = ((size_t)b*PN2 + (iy + 4)*PW2 + ix + 4)*CHN;
    #pragma unroll
    for (int cc = 0; cc < 8; ++cc) {
        int c = c0 + cc;
        float Ov = 0.f;
        #pragma unroll
        for (int k = 0; k < NQTR; ++k)
            Ov += Opg[ob + (size_t)k*2048 + c];
        AT[atb + c] = Ov*inv + FR[frb + c];
    }
}

// ---------------------------------------------------------------------------
// conv 9x9 (64 -> 3) + tanh. Wave per 4 pixels, lane = ci.
__global__ __launch_bounds__(256) void k_conv_out(const float* __restrict__ AT,
        const float* __restrict__ Wo, const float* __restrict__ bias,
        float* __restrict__ out) {
    int t = threadIdx.x;
    int w = t >> 6, lane = t & 63;
    int base = blockIdx.x*16 + w*4;
    int b = base / NSP;
    int n0 = base % NSP;
    int y0 = n0 / WW, x0 = n0 % WW;

    float s[4][3] = {{0,0,0},{0,0,0},{0,0,0},{0,0,0}};
    for (int ky = 0; ky < 9; ++ky) {
        const float* arow = AT + ((size_t)b*PN2 + (size_t)(y0 + ky)*PW2 + x0)*CHN + lane;
        const float* wrow = Wo + (size_t)ky*9*192;
        float xv[12];
        #pragma unroll
        for (int u = 0; u < 12; ++u)
            xv[u] = arow[(size_t)u*CHN];
        #pragma unroll
        for (int kx = 0; kx < 9; ++kx) {
            float w0 = wrow[kx*192 +   0 + lane];
            float w1 = wrow[kx*192 +  64 + lane];
            float w2 = wrow[kx*192 + 128 + lane];
            #pragma unroll
            for (int p = 0; p < 4; ++p) {
                float x = xv[kx + p];
                s[p][0] = fmaf(x, w0, s[p][0]);
                s[p][1] = fmaf(x, w1, s[p][1]);
                s[p][2] = fmaf(x, w2, s[p][2]);
            }
        }
    }
    #pragma unroll
    for (int p = 0; p < 4; ++p)
        #pragma unroll
        for (int c = 0; c < 3; ++c) {
            float v = s[p][c];
            v += __shfl_xor(v, 1);
            v += __shfl_xor(v, 2);
            v += __shfl_xor(v, 4);
            v += __shfl_xor(v, 8);
            v += __shfl_xor(v, 16);
            v += __shfl_xor(v, 32);
            s[p][c] = v;
        }
    #pragma unroll
    for (int p = 0; p < 4; ++p)
        #pragma unroll
        for (int c = 0; c < 3; ++c)
            if (lane == p*3 + c)
                out[((size_t)(b*3 + c))*NSP + n0 + p] = tanhf(s[p][c] + bias[c]);
}

// ---------------------------------------------------------------------------
extern "C" void kernel_launch(void* const* d_in, const int* in_sizes, int n_in,
                              void* d_out, int out_size, void* d_ws, size_t ws_size,
                              hipStream_t stream) {
    (void)in_sizes; (void)n_in; (void)out_size; (void)ws_size;
    const float* x     = (const float*)d_in[0];
    const float* w_in  = (const float*)d_in[1];
    const float* b_in  = (const float*)d_in[2];
    const float* a_in  = (const float*)d_in[3];
    const float* rw1   = (const float*)d_in[4];
    const float* rb1   = (const float*)d_in[5];
    const float* ra    = (const float*)d_in[6];
    const float* rw2   = (const float*)d_in[7];
    const float* rb2   = (const float*)d_in[8];
    const float* wq    = (const float*)d_in[9];
    const float* bq    = (const float*)d_in[10];
    const float* wk    = (const float*)d_in[11];
    const float* bk    = (const float*)d_in[12];
    const float* wv    = (const float*)d_in[13];
    const float* bv    = (const float*)d_in[14];
    const float* gamma = (const float*)d_in[15];
    const float* w_out = (const float*)d_in[16];
    const float* b_out = (const float*)d_in[17];

    const size_t SZ_FR  = (size_t)BATCH*PN*CHN*4;        // 4,917,248
    const size_t SZ_FBI = (size_t)BATCH*FBST*2;          // 5,048,320
    const size_t SZ_WT  = (size_t)NBLK*2*9*CHN*CHN*2;    //   737,280
    const size_t SZ_QK  = (size_t)BATCH*NSP*C8*2;        //   294,912
    const size_t SZ_VB  = (size_t)BATCH*CHN*NSP*2;       // 2,359,296
    const size_t SZ_AT  = (size_t)BATCH*PN2*CHN*4;       // 5,537,792
    const size_t SZ_WO  = (size_t)81*CIN*CHN*4;          //    62,208
    const size_t SZ_WIN = (size_t)243*CHN*4;             //    62,208
    const size_t SZ_WQ  = (size_t)80*CHN*2;              //    10,240
    const size_t SZ_OP  = (size_t)BATCH*NRB*NQTR*2048*4; // 28,311,552
    const size_t SZ_LG  = (size_t)BATCH*NRB*NQTR*32*4;   //   442,368
    const size_t SZ_KI  = (size_t)8*KPAD*4;              //       512
    char* p = (char*)d_ws;
    float* FR      = (float*)p;           p += SZ_FR;
    short* FBI0raw = (short*)p;           p += SZ_FBI;
    short* FBI1raw = (short*)p;           p += SZ_FBI;
    short* Whi     = (short*)p;           p += SZ_WT;
    short* Wlo     = (short*)p;           p += SZ_WT;
    short* Qb16    = (short*)p;           p += SZ_QK;
    short* Kb16    = (short*)p;           p += SZ_QK;
    short* Vb16    = (short*)p;           p += SZ_VB;
    float* AT      = (float*)p;           p += SZ_AT;
    float* Wo      = (float*)p;           p += SZ_WO;
    float* Win     = (float*)p;           p += SZ_WIN;
    short* Wqh     = (short*)p;           p += SZ_WQ;
    short* Wql     = (short*)p;           p += SZ_WQ;
    float* Opg     = (float*)p;           p += SZ_OP;
    float* lgb     = (float*)p;           p += SZ_LG;
    float* Kinf    = (float*)p;           p += SZ_KI;
    short* FBI0 = FBI0raw + (size_t)GUARD*128;
    short* FBI1 = FBI1raw + (size_t)GUARD*128;
    float* outp = (float*)d_out;

    // FR memset dropped: every FR element read (conv3 mode-1 interior,
    // attn_fin interior) is written by k_conv_in first.
    hipMemsetAsync(FBI0raw, 0, SZ_FBI, stream);
    hipMemsetAsync(FBI1raw, 0, SZ_FBI, stream);
    hipMemsetAsync(AT, 0, SZ_AT, stream);
    hipMemsetAsync(Kinf, 0, SZ_KI, stream);

    dim3 blk(256);

    const int PREP_TOT = NBLK*2*9*CHN*CHN + 80*CHN + 81*CIN*CHN + 243*CHN;
    k_prep_all<<<(PREP_TOT + 255)/256, blk, 0, stream>>>(
        rw1, rw2, Whi, Wlo, wq, wk, wv, Wqh, Wql, w_out, Wo, w_in, Win);
    k_conv_in<<<BATCH*96*3*2, blk, 0, stream>>>(x, Win, b_in, a_in, FR, FBI0);
    for (int i = 0; i < NBLK; ++i) {
        k_conv3_mfma<<<BATCH*576, blk, 0, stream>>>(
            FBI0,
            Whi + (size_t)(2*i)*9*CHN*CHN, Wlo + (size_t)(2*i)*9*CHN*CHN,
            rb1 + i*CHN, ra + i, (float*)nullptr, FBI1, 0);
        k_conv3_mfma<<<BATCH*576, blk, 0, stream>>>(
            FBI1,
            Whi + (size_t)(2*i+1)*9*CHN*CHN, Wlo + (size_t)(2*i+1)*9*CHN*CHN,
            rb2 + i*CHN, ra + i, FR, FBI0, 1);
    }
    k_qkv_mfma<<<BATCH*NCHK, blk, 0, stream>>>(
        FBI0, Wqh, Wql, bq, bk, bv, Qb16, Kb16, Vb16, Kinf);
    k_attn_mfma<<<BATCH*NRB*NQTR, blk, 0, stream>>>(
        Qb16, Kb16, Vb16, Kinf, Opg, lgb);
    k_attn_fin<<<BATCH*NRB, blk, 0, stream>>>(Opg, lgb, FR, gamma, AT);
    k_conv_out<<<(BATCH*NSP)/16, blk, 0, stream>>>(AT, Wo, b_out, outp);
}

// Round 9
// 332.291 us; speedup vs baseline: 1.4010x; 1.4010x over previous
//
#include <hip/hip_runtime.h>
#include <cmath>

#define BATCH 2
#define CIN 3
#define HH 96
#define WW 96
#define NSP (HH*WW)      // 9216
#define CHN 64
#define C8 8
#define NBLK 5

#define PW 98            // padded width/height (3x3 convs)
#define PN (PW*PW)       // 9604 padded spatial
#define GUARD 128        // guard rows (spatial) each side of FBI buffers
#define FBST ((PN + 2*GUARD)*128)  // shorts per batch in FBI (hi|lo interleaved)

#define PW2 104          // padded width for 9x9 conv_out input
#define PN2 (PW2*PW2)    // 10816

#define NRB (NSP/32)     // 288 row-blocks in attention
#define NCHK 144         // 64-col j-chunks (9216/64)
#define NQTR 4           // j split across 4 blocks (reverted: 6 gave no
                         // occupancy gain, doubled FETCH, +2.3us)

#define KPAD 16          // Kinf padded stride (floats) -> 1 entry per 64B line

#define LOG2E 1.4426950408889634f
#define BOOST 100.0f     // exponent boost: p' = 2^(e-M+BOOST), overflow-safe

typedef __attribute__((ext_vector_type(8))) short bf16x8;
typedef __attribute__((ext_vector_type(4))) float f32x4;

static __device__ __forceinline__ short f2b(float f) {
    union { float f; unsigned u; } v; v.f = f;
    unsigned r = (v.u + 0x7FFFu + ((v.u >> 16) & 1u)) >> 16;
    return (short)r;
}
static __device__ __forceinline__ float b2f(short s) {
    union { unsigned u; float f; } v; v.u = ((unsigned)(unsigned short)s) << 16;
    return v.f;
}
static __device__ __forceinline__ void split2(float v, short& hi, short& lo) {
    hi = f2b(v);
    lo = f2b(v - b2f(hi));
}

// ---------------------------------------------------------------------------
// merged weight prep. Conv3 weights now in MFMA FRAGMENT ORDER:
//   Whi[conv][kyx][ct][cih][lane][8],  lane=(q<<4)|n16,
//   element = W[co=ct*16+n16][ci=cih*32+q*8+e]
// so conv3's weight loads are wave-uniform base + lane*16B (1KB contiguous,
// 16 cache lines) instead of 128B-stride scatters (64 lines/load — that
// scatter was ~17us/CU of line transactions per conv3 dispatch).
// Same fragment order for qkv weights: Wq[ct(5)][cih][lane][8].
__global__ __launch_bounds__(256) void k_prep_all(
        const float* __restrict__ rw1, const float* __restrict__ rw2,
        short* __restrict__ Whi, short* __restrict__ Wlo,
        const float* __restrict__ wq, const float* __restrict__ wk,
        const float* __restrict__ wv,
        short* __restrict__ Wqh, short* __restrict__ Wql,
        const float* __restrict__ w_out, float* __restrict__ Wo,
        const float* __restrict__ w_in, float* __restrict__ Win) {
    int idx = blockIdx.x * 256 + threadIdx.x;
    const int TOT_A = NBLK*2*9*CHN*CHN;   // 368640 = 10*9*4*2*64*8
    const int TOT_B = 80*CHN;             //   5120 = 5*2*64*8
    const int TOT_C = 81*CIN*CHN;         //  15552
    if (idx < TOT_A) {
        int e   = idx & 7;
        int l   = (idx >> 3) & 63;
        int cih = (idx >> 9) & 1;
        int ct  = (idx >> 10) & 3;
        int r2  = idx >> 12;              // 0..89
        int kyx = r2 % 9;
        int conv = r2 / 9;
        int blk = conv >> 1, s = conv & 1;
        int co = ct*16 + (l & 15);
        int ci = cih*32 + ((l >> 4) << 3) + e;
        const float* src = s ? rw2 : rw1;
        float v = src[(((size_t)(blk*CHN + co))*CHN + ci)*9 + kyx];
        short h, lo; split2(v, h, lo);
        Whi[idx] = h; Wlo[idx] = lo;
        return;
    }
    idx -= TOT_A;
    if (idx < TOT_B) {
        int e   = idx & 7;
        int l   = (idx >> 3) & 63;
        int cih = (idx >> 9) & 1;
        int ct  = idx >> 10;              // 0..4
        int co = ct*16 + (l & 15);
        int ci = cih*32 + ((l >> 4) << 3) + e;
        float v;
        if (co < 8)       v = wq[co*CHN + ci];
        else if (co < 16) v = wk[(co-8)*CHN + ci];
        else              v = wv[(co-16)*CHN + ci];
        short h, lo; split2(v, h, lo);
        Wqh[idx] = h; Wql[idx] = lo;
        return;
    }
    idx -= TOT_B;
    if (idx < TOT_C) {
        int ci = idx & 63;
        int co = (idx >> 6) % 3;
        int kyx = idx / 192;
        Wo[idx] = w_out[((size_t)(co*CHN + ci))*81 + kyx];
        return;
    }
    idx -= TOT_C;
    if (idx < 243*CHN) {
        int co = idx & 63;
        int k  = idx >> 6;          // 0..242
        int ci = k / 81, kk = k % 81;
        Win[idx] = w_in[((size_t)(co*CIN + ci))*81 + kk];
    }
}

// ---------------------------------------------------------------------------
// conv 9x9 (3 -> 64), pad 4, + PReLU. x window staged once in LDS.
// XCD-swizzled (y-slab per XCD, matches conv3's mapping).
__global__ __launch_bounds__(256) void k_conv_in(const float* __restrict__ x,
        const float* __restrict__ Win, const float* __restrict__ bias,
        const float* __restrict__ a, float* __restrict__ FR,
        short* __restrict__ FBI) {
    __shared__ float xw[3*9*40];     // [ci][ky][c], c = xs-(x0-4), 4320 B
    int t = threadIdx.x;
    int blk = blockIdx.x;
    int xcd = blk & 7;
    int l   = blk >> 3;              // 0..143 = b(2) x y%12(12) x s(6)
    int b   = l / 72;
    int r   = l % 72;
    int y   = xcd*12 + r/6;
    int s   = r % 6;                 // xc*2 + coh
    int xc  = s >> 1;
    int coh = s & 1;
    int x0 = xc*32;
    int px  = t & 31;
    int cog = t >> 5;                // 8 groups x 4 co (within this half)

    // ---- stage x window: rows y-4..y+4, cols x0-4..x0+35, 3 ci ----
    #pragma unroll
    for (int u = 0; u < 5; ++u) {
        int idx = u*256 + t;
        if (idx < 1080) {
            int ci = idx / 360;
            int rr = idx - ci*360;
            int ky = rr / 40;
            int c  = rr - ky*40;
            int yy = y + ky - 4;
            int xs = x0 + c - 4;
            float v = 0.f;
            if (yy >= 0 && yy < 96 && xs >= 0 && xs < 96)
                v = x[((size_t)(b*CIN + ci))*NSP + yy*96 + xs];
            xw[idx] = v;
        }
    }
    __syncthreads();

    int cbase = coh*32 + cog*4;
    float acc[4];
    #pragma unroll
    for (int rr = 0; rr < 4; ++rr) acc[rr] = bias[cbase + rr];

    #pragma unroll 1
    for (int ci = 0; ci < CIN; ++ci) {
        #pragma unroll 1
        for (int ky = 0; ky < 9; ++ky) {
            const float* xrow = xw + (ci*9 + ky)*40 + px;
            const float* wrow = Win + (size_t)(ci*81 + ky*9)*64 + cbase;
            float xv[9];
            #pragma unroll
            for (int kx = 0; kx < 9; ++kx) xv[kx] = xrow[kx];
            #pragma unroll
            for (int kx = 0; kx < 9; ++kx) {
                float4 wv = *(const float4*)(wrow + kx*64);
                acc[0] = fmaf(xv[kx], wv.x, acc[0]);
                acc[1] = fmaf(xv[kx], wv.y, acc[1]);
                acc[2] = fmaf(xv[kx], wv.z, acc[2]);
                acc[3] = fmaf(xv[kx], wv.w, acc[3]);
            }
        }
    }
    float sl = a[0];
    #pragma unroll
    for (int rr = 0; rr < 4; ++rr) {
        float v = acc[rr];
        acc[rr] = v >= 0.f ? v : sl*v;
    }
    int np = (y + 1)*PW + x0 + px + 1;
    float* fr = FR + ((size_t)b*PN + np)*CHN + cbase;
    *(float4*)fr = make_float4(acc[0], acc[1], acc[2], acc[3]);
    union { short ss[4]; short4 v4; } h4, l4;
    #pragma unroll
    for (int rr = 0; rr < 4; ++rr) split2(acc[rr], h4.ss[rr], l4.ss[rr]);
    short* fo = FBI + (size_t)b*FBST + (size_t)np*128 + cbase;
    *(short4*)fo        = h4.v4;
    *(short4*)(fo + 64) = l4.v4;
}

// ---------------------------------------------------------------------------
// 3x3 conv 64->64, implicit GEMM, split-bf16 3-MFMA, XCD-swizzled.
// Weight loads now FRAGMENT-ORDER CONTIGUOUS (base + lane*16B = 1KB/inst).
__global__ __launch_bounds__(256, 4) void k_conv3_mfma(
        const short* __restrict__ FBin,
        const short* __restrict__ Whi, const short* __restrict__ Wlo,
        const float* __restrict__ bias, const float* __restrict__ slope_p,
        float* __restrict__ FR, short* __restrict__ FBout, int mode) {
    __shared__ short xs[3*18*128];   // 13,824 B
    char* xb = (char*)xs;
    int t = threadIdx.x;
    int w = t >> 6, lane = t & 63;
    int q = lane >> 4, n16 = lane & 15;
    int blk = blockIdx.x;
    int xcd = blk & 7;
    int l   = blk >> 3;              // 0..143 = b(2) x y%12(12) x xchunk(6)
    int b   = l / 72;
    int rem = l % 72;
    int y   = xcd*12 + rem/6;
    int x0  = (rem % 6)*16;

    const short* fbB = FBin + (size_t)b*FBST;

    // ---- stage: 864 16-B granules, swizzled into LDS ----
    #pragma unroll
    for (int k = 0; k < 4; ++k) {
        int u = k*256 + t;
        if (u < 864) {
            int px_lin = u >> 4, G = u & 15;
            int r = px_lin / 18, p = px_lin - r*18;
            const float4 src = *(const float4*)(fbB
                + ((size_t)((y + r)*PW + x0 + p))*128 + G*8);
            *(float4*)(xb + (px_lin << 8) + ((G ^ (px_lin & 15)) << 4)) = src;
        }
    }
    __syncthreads();

    // ---- compute: wave = 16 px x 16 co (ct = w) ----
    int ct = w;
    f32x4 acc = {0,0,0,0};

    #pragma unroll
    for (int dy = 0; dy < 3; ++dy) {
        #pragma unroll
        for (int dx = 0; dx < 3; ++dx) {
            int kyx = dy*3 + dx;
            int px_lin = dy*18 + n16 + dx;
            int pbase = px_lin << 8;
            int sw = px_lin & 15;
            #pragma unroll
            for (int cih = 0; cih < 2; ++cih) {
                int Gh = cih*4 + q;
                int Gl = 8 + cih*4 + q;
                bf16x8 bhi = *(const bf16x8*)(xb + pbase + ((Gh ^ sw) << 4));
                bf16x8 blo = *(const bf16x8*)(xb + pbase + ((Gl ^ sw) << 4));
                size_t woff = ((size_t)((kyx*4 + ct)*2 + cih)*64 + lane)*8;
                bf16x8 ahi = *(const bf16x8*)(Whi + woff);
                bf16x8 alo = *(const bf16x8*)(Wlo + woff);
                acc = __builtin_amdgcn_mfma_f32_16x16x32_bf16(ahi, bhi, acc, 0, 0, 0);
                acc = __builtin_amdgcn_mfma_f32_16x16x32_bf16(ahi, blo, acc, 0, 0, 0);
                acc = __builtin_amdgcn_mfma_f32_16x16x32_bf16(alo, bhi, acc, 0, 0, 0);
            }
        }
    }

    // ---- epilogue: all outputs interior, vectorized stores ----
    int nb = (y + 1)*PW + x0 + 1 + n16;
    float sl = slope_p[0];
    short* fbo = FBout + (size_t)b*FBST + (size_t)nb*128;
    int co0 = ct*16 + q*4;
    float v[4];
    #pragma unroll
    for (int r = 0; r < 4; ++r) v[r] = acc[r] + bias[co0 + r];
    if (mode == 0) {
        #pragma unroll
        for (int r = 0; r < 4; ++r) v[r] = v[r] >= 0.f ? v[r] : sl*v[r];
    } else {
        float* fr = FR + ((size_t)b*PN + nb)*CHN + co0;
        float4 f = *(const float4*)fr;
        v[0] += f.x; v[1] += f.y; v[2] += f.z; v[3] += f.w;
        *(float4*)fr = make_float4(v[0], v[1], v[2], v[3]);
    }
    union { short s[4]; short4 v4; } h4, l4;
    #pragma unroll
    for (int r = 0; r < 4; ++r) split2(v[r], h4.s[r], l4.s[r]);
    *(short4*)(fbo + co0)      = h4.v4;
    *(short4*)(fbo + 64 + co0) = l4.v4;
}

// ---------------------------------------------------------------------------
// qkv projection as 1x1-conv implicit GEMM. N-space aligned blocks
// (coalesced V fragment stores). Weight loads fragment-order contiguous.
__global__ __launch_bounds__(256) void k_qkv_mfma(
        const short* __restrict__ FBin,
        const short* __restrict__ Wh, const short* __restrict__ Wl,
        const float* __restrict__ bq, const float* __restrict__ bk,
        const float* __restrict__ bv,
        short* __restrict__ Qb, short* __restrict__ Kb, short* __restrict__ Vb,
        float* __restrict__ Kinf) {
    __shared__ float kls[4][8];
    int t = threadIdx.x;
    int w = t >> 6, lane = t & 63;
    int q = lane >> 4, n16 = lane & 15;
    int blk = blockIdx.x;
    int b = blk / NCHK, chunk = blk % NCHK;
    int n  = chunk*64 + w*16 + n16;          // 0..9215, always valid
    int iy = n / WW, ix = n - iy*WW;
    int nb = (iy + 1)*PW + ix + 1;

    const short* fb = FBin + (size_t)b*FBST;
    f32x4 acc[5] = {{0,0,0,0},{0,0,0,0},{0,0,0,0},{0,0,0,0},{0,0,0,0}};

    int nbase = nb*128;
    #pragma unroll
    for (int cih = 0; cih < 2; ++cih) {
        bf16x8 bhi = *(const bf16x8*)(fb + nbase + cih*32 + q*8);
        bf16x8 blo = *(const bf16x8*)(fb + nbase + 64 + cih*32 + q*8);
        #pragma unroll
        for (int ct = 0; ct < 5; ++ct) {
            size_t aoff = ((size_t)(ct*2 + cih)*64 + lane)*8;
            bf16x8 ahi = *(const bf16x8*)(Wh + aoff);
            bf16x8 alo = *(const bf16x8*)(Wl + aoff);
            acc[ct] = __builtin_amdgcn_mfma_f32_16x16x32_bf16(ahi, bhi, acc[ct], 0, 0, 0);
            acc[ct] = __builtin_amdgcn_mfma_f32_16x16x32_bf16(ahi, blo, acc[ct], 0, 0, 0);
            acc[ct] = __builtin_amdgcn_mfma_f32_16x16x32_bf16(alo, bhi, acc[ct], 0, 0, 0);
        }
    }

    int jin = w*16 + n16;                    // j within chunk, wave-local
    float kabs[4] = {0.f, 0.f, 0.f, 0.f};
    union { short s[4]; short4 v4; } pk;
    if (q < 2) {
        #pragma unroll
        for (int r = 0; r < 4; ++r)
            pk.s[r] = f2b((acc[0][r] + bq[q*4 + r]) * LOG2E);
        *(short4*)(Qb + ((size_t)b*NSP + n)*8 + q*4) = pk.v4;
    } else {
        // K fragment coords (inverse of attn's jrow mapping)
        int ttk  = ((jin >> 5) << 1) | ((jin >> 2) & 1);
        int n16k = (((jin >> 3) & 3) << 2) | (jin & 3);
        size_t kbase = (((size_t)(b*NCHK + chunk)*4 + ttk)*16 + n16k)*8;
        #pragma unroll
        for (int r = 0; r < 4; ++r) {
            float kv = acc[0][r] + bk[(q - 2)*4 + r];
            kabs[r] = fabsf(kv) * 1.01f;
            pk.s[r] = f2b(kv);
        }
        *(short4*)(Kb + kbase + (q - 2)*4) = pk.v4;
    }
    // V fragment coords (j = ks*32 + quad*8 + e within chunk)
    int ksv = jin >> 5, qv = (jin >> 3) & 3, ev = jin & 7;
    size_t vbase = ((size_t)(b*NCHK + chunk)*2 + ksv)*2048 + qv*128 + ev;
    #pragma unroll
    for (int ct = 1; ct < 5; ++ct) {
        #pragma unroll
        for (int r = 0; r < 4; ++r) {
            int co = ct*16 + q*4 + r;
            Vb[vbase + (size_t)(ct - 1)*512 + (q*4 + r)*8] =
                f2b(acc[ct][r] + bv[co - 16]);
        }
    }
    #pragma unroll
    for (int r = 0; r < 4; ++r) {
        #pragma unroll
        for (int off = 1; off < 16; off <<= 1)
            kabs[r] = fmaxf(kabs[r], __shfl_xor(kabs[r], off));
    }
    if (q >= 2 && n16 == 0) {
        #pragma unroll
        for (int r = 0; r < 4; ++r)
            kls[w][(q - 2)*4 + r] = kabs[r];
    }
    __syncthreads();
    if (t < 8) {
        float m = fmaxf(fmaxf(kls[0][t], kls[1][t]),
                        fmaxf(kls[2][t], kls[3][t]));
        atomicMax((int*)&Kinf[t*KPAD], __float_as_int(m));
    }
}

// ---------------------------------------------------------------------------
// chunk buffer for attention (single-buffered: TLP beats ILP here — both
// the full dbuf (r2) and K-prefetch (r6) variants lost to occupancy).
struct CB { bf16x8 kf[4]; bf16x8 vf[8]; };

static __device__ __forceinline__ void attn_load(CB& cb,
        const short* __restrict__ KpJ, const short* __restrict__ VpJ,
        int n16, int lane) {
    #pragma unroll
    for (int tt = 0; tt < 4; ++tt)
        cb.kf[tt] = *(const bf16x8*)(KpJ + tt*128 + n16*8);
    #pragma unroll
    for (int ks = 0; ks < 2; ++ks)
        #pragma unroll
        for (int ct = 0; ct < 4; ++ct)
            cb.vf[ks*4 + ct] = *(const bf16x8*)(VpJ + (ks*4 + ct)*512 + lane*8);
}

static __device__ __forceinline__ void attn_compute(const CB& cb,
        const bf16x8 (&qf)[2], const f32x4 (&ci)[2],
        f32x4 (&accO)[2][4], float (&lp)[2]) {
    union PB { int di[8]; bf16x8 v8[2]; };
    PB pb[2];
    #pragma unroll
    for (int rg = 0; rg < 2; ++rg) {
        f32x4 e[4];
        #pragma unroll
        for (int tt = 0; tt < 4; ++tt)
            e[tt] = __builtin_amdgcn_mfma_f32_16x16x32_bf16(
                cb.kf[tt], qf[rg], ci[rg], 0, 0, 0);
        float st[4];
        #pragma unroll
        for (int tt = 0; tt < 4; ++tt) {
            #pragma unroll
            for (int r = 0; r < 4; ++r)
                e[tt][r] = __builtin_amdgcn_exp2f(e[tt][r]);
            st[tt] = (e[tt][0] + e[tt][1]) + (e[tt][2] + e[tt][3]);
        }
        lp[rg] += (st[0] + st[1]) + (st[2] + st[3]);
        // pack P to bf16 fragments eagerly (frees the 16 f32 e regs)
        #pragma unroll
        for (int tt = 0; tt < 4; ++tt) {
            pb[rg].di[tt*2]   = __builtin_amdgcn_perm(__float_as_uint(e[tt][1]),
                                             __float_as_uint(e[tt][0]), 0x07060302u);
            pb[rg].di[tt*2+1] = __builtin_amdgcn_perm(__float_as_uint(e[tt][3]),
                                             __float_as_uint(e[tt][2]), 0x07060302u);
        }
    }
    #pragma unroll
    for (int ks = 0; ks < 2; ++ks)
        #pragma unroll
        for (int rg = 0; rg < 2; ++rg)
            #pragma unroll
            for (int ct = 0; ct < 4; ++ct)
                accO[rg][ct] = __builtin_amdgcn_mfma_f32_16x16x32_bf16(
                    pb[rg].v8[ks], cb.vf[ks*4 + ct], accO[rg][ct], 0, 0, 0);
}

// MFMA flash attention, bound-based softmax, j split across 4 blocks
// (grid 2304 = 9 blocks/CU; NQTR=6 tried r7: no occupancy gain, 2x FETCH).
__global__ __launch_bounds__(256) void k_attn_mfma(
        const short* __restrict__ Qb, const short* __restrict__ Kb,
        const short* __restrict__ Vb, const float* __restrict__ Kinf_p,
        float* __restrict__ Opg, float* __restrict__ lg) {
    __shared__ float Opart[4][16][68];
    __shared__ float lsh[4][2][16];

    int blk = blockIdx.x;
    int b    = blk / (NRB*NQTR);
    int rem  = blk % (NRB*NQTR);
    int rb   = rem / NQTR;
    int qtr  = rem % NQTR;
    int i0 = rb*32;
    int t = threadIdx.x;
    int w = t >> 6;
    int lane = t & 63;
    int quad = lane >> 4, n16 = lane & 15;

    const short* Qp = Qb + ((size_t)b*NSP)*8;
    const short* Kp = Kb + ((size_t)b*NSP)*8;
    const short* Vp = Vb + ((size_t)b*CHN)*NSP;

    bf16x8 qf[2];
    float Mi[2];
    #pragma unroll
    for (int rg = 0; rg < 2; ++rg) {
        bf16x8 z = {0,0,0,0,0,0,0,0};
        qf[rg] = z;
        if (quad == 0)
            qf[rg] = *(const bf16x8*)(Qp + (size_t)(i0 + rg*16 + n16)*8);
        float s1 = 0.f;
        #pragma unroll
        for (int c = 0; c < 8; ++c)
            s1 += fabsf(b2f(qf[rg][c])) * Kinf_p[c*KPAD];
        float Mv = s1 + 1.0f - BOOST;
        Mi[rg] = __shfl(Mv, n16);
    }

    f32x4 accO[2][4] = {{{0,0,0,0},{0,0,0,0},{0,0,0,0},{0,0,0,0}},
                        {{0,0,0,0},{0,0,0,0},{0,0,0,0},{0,0,0,0}}};
    float lp[2] = {0.f, 0.f};
    f32x4 ci[2];
    #pragma unroll
    for (int rg = 0; rg < 2; ++rg) {
        ci[rg][0] = -Mi[rg]; ci[rg][1] = -Mi[rg];
        ci[rg][2] = -Mi[rg]; ci[rg][3] = -Mi[rg];
    }

    // wave w covers 9 chunks of 64 j within its quarter
    int Jb = qtr*36 + w*9;
    const short* KpJ = Kp + (size_t)Jb*512;
    const short* VpJ = Vp + (size_t)Jb*4096;

    #pragma unroll 1
    for (int jc = 0; jc < 9; ++jc) {
        CB cb;
        attn_load(cb, KpJ, VpJ, n16, lane);
        attn_compute(cb, qf, ci, accO, lp);
        KpJ += 512;
        VpJ += 4096;
    }

    // ---- epilogue: cross-wave reduce, rg-looped to halve LDS ----
    #pragma unroll
    for (int rg = 0; rg < 2; ++rg) {
        float l = lp[rg];
        l += __shfl_xor(l, 16);
        l += __shfl_xor(l, 32);
        if (quad == 0) lsh[w][rg][n16] = l;
    }

    size_t obase = (((size_t)(b*NRB + rb))*NQTR + qtr)*2048;
    int row16 = t >> 4;          // 0..15
    int c0 = (t & 15)*4;
    #pragma unroll
    for (int rg = 0; rg < 2; ++rg) {
        if (rg) __syncthreads();
        #pragma unroll
        for (int ct = 0; ct < 4; ++ct)
            #pragma unroll
            for (int r = 0; r < 4; ++r)
                Opart[w][quad*4 + r][ct*16 + n16] = accO[rg][ct][r];
        __syncthreads();
        #pragma unroll
        for (int cc = 0; cc < 4; ++cc) {
            int c = c0 + cc;
            Opg[obase + (size_t)(rg*16 + row16)*64 + c] =
                Opart[0][row16][c] + Opart[1][row16][c]
              + Opart[2][row16][c] + Opart[3][row16][c];
        }
    }
    if (t < 32) {
        int rgl = t >> 4, ii = t & 15;
        lg[(((size_t)(b*NRB + rb))*NQTR + qtr)*32 + t] =
            lsh[0][rgl][ii] + lsh[1][rgl][ii]
          + lsh[2][rgl][ii] + lsh[3][rgl][ii];
    }
}

// ---------------------------------------------------------------------------
// attention finalize: merge j-quarters, normalize, add residual, write AT.
__global__ __launch_bounds__(256) void k_attn_fin(
        const float* __restrict__ Opg, const float* __restrict__ lg,
        const float* __restrict__ FR, const float* __restrict__ gamma_p,
        float* __restrict__ AT) {
    int blk = blockIdx.x;            // b*NRB + rb
    int b = blk / NRB, rb = blk % NRB;
    int t = threadIdx.x;
    int row = t >> 3;
    int c0 = (t & 7)*8;
    float g = gamma_p[0];
    size_t ob = ((size_t)blk*NQTR)*2048 + (size_t)row*64;
    float l = 0.f;
    #pragma unroll
    for (int k = 0; k < NQTR; ++k)
        l += lg[((size_t)blk*NQTR + k)*32 + row];
    float inv = g / fmaxf(l, 1e-35f);
    int gi = rb*32 + row;
    int iy = gi / WW, ix = gi - iy*WW;
    size_t frb = ((size_t)b*PN + (iy + 1)*PW + ix + 1)*CHN;
    size_t atb = ((size_t)b*PN2 + (iy + 4)*PW2 + ix + 4)*CHN;
    #pragma unroll
    for (int cc = 0; cc < 8; ++cc) {
        int c = c0 + cc;
        float Ov = 0.f;
        #pragma unroll
        for (int k = 0; k < NQTR; ++k)
            Ov += Opg[ob + (size_t)k*2048 + c];
        AT[atb + c] = Ov*inv + FR[frb + c];
    }
}

// ---------------------------------------------------------------------------
// conv 9x9 (64 -> 3) + tanh. Wave per 4 pixels, lane = ci.
__global__ __launch_bounds__(256) void k_conv_out(const float* __restrict__ AT,
        const float* __restrict__ Wo, const float* __restrict__ bias,
        float* __restrict__ out) {
    int t = threadIdx.x;
    int w = t >> 6, lane = t & 63;
    int base = blockIdx.x*16 + w*4;
    int b = base / NSP;
    int n0 = base % NSP;
    int y0 = n0 / WW, x0 = n0 % WW;

    float s[4][3] = {{0,0,0},{0,0,0},{0,0,0},{0,0,0}};
    for (int ky = 0; ky < 9; ++ky) {
        const float* arow = AT + ((size_t)b*PN2 + (size_t)(y0 + ky)*PW2 + x0)*CHN + lane;
        const float* wrow = Wo + (size_t)ky*9*192;
        float xv[12];
        #pragma unroll
        for (int u = 0; u < 12; ++u)
            xv[u] = arow[(size_t)u*CHN];
        #pragma unroll
        for (int kx = 0; kx < 9; ++kx) {
            float w0 = wrow[kx*192 +   0 + lane];
            float w1 = wrow[kx*192 +  64 + lane];
            float w2 = wrow[kx*192 + 128 + lane];
            #pragma unroll
            for (int p = 0; p < 4; ++p) {
                float x = xv[kx + p];
                s[p][0] = fmaf(x, w0, s[p][0]);
                s[p][1] = fmaf(x, w1, s[p][1]);
                s[p][2] = fmaf(x, w2, s[p][2]);
            }
        }
    }
    #pragma unroll
    for (int p = 0; p < 4; ++p)
        #pragma unroll
        for (int c = 0; c < 3; ++c) {
            float v = s[p][c];
            v += __shfl_xor(v, 1);
            v += __shfl_xor(v, 2);
            v += __shfl_xor(v, 4);
            v += __shfl_xor(v, 8);
            v += __shfl_xor(v, 16);
            v += __shfl_xor(v, 32);
            s[p][c] = v;
        }
    #pragma unroll
    for (int p = 0; p < 4; ++p)
        #pragma unroll
        for (int c = 0; c < 3; ++c)
            if (lane == p*3 + c)
                out[((size_t)(b*3 + c))*NSP + n0 + p] = tanhf(s[p][c] + bias[c]);
}

// ---------------------------------------------------------------------------
extern "C" void kernel_launch(void* const* d_in, const int* in_sizes, int n_in,
                              void* d_out, int out_size, void* d_ws, size_t ws_size,
                              hipStream_t stream) {
    (void)in_sizes; (void)n_in; (void)out_size; (void)ws_size;
    const float* x     = (const float*)d_in[0];
    const float* w_in  = (const float*)d_in[1];
    const float* b_in  = (const float*)d_in[2];
    const float* a_in  = (const float*)d_in[3];
    const float* rw1   = (const float*)d_in[4];
    const float* rb1   = (const float*)d_in[5];
    const float* ra    = (const float*)d_in[6];
    const float* rw2   = (const float*)d_in[7];
    const float* rb2   = (const float*)d_in[8];
    const float* wq    = (const float*)d_in[9];
    const float* bq    = (const float*)d_in[10];
    const float* wk    = (const float*)d_in[11];
    const float* bk    = (const float*)d_in[12];
    const float* wv    = (const float*)d_in[13];
    const float* bv    = (const float*)d_in[14];
    const float* gamma = (const float*)d_in[15];
    const float* w_out = (const float*)d_in[16];
    const float* b_out = (const float*)d_in[17];

    const size_t SZ_FR  = (size_t)BATCH*PN*CHN*4;        // 4,917,248
    const size_t SZ_FBI = (size_t)BATCH*FBST*2;          // 5,048,320
    const size_t SZ_WT  = (size_t)NBLK*2*9*CHN*CHN*2;    //   737,280
    const size_t SZ_QK  = (size_t)BATCH*NSP*C8*2;        //   294,912
    const size_t SZ_VB  = (size_t)BATCH*CHN*NSP*2;       // 2,359,296
    const size_t SZ_AT  = (size_t)BATCH*PN2*CHN*4;       // 5,537,792
    const size_t SZ_WO  = (size_t)81*CIN*CHN*4;          //    62,208
    const size_t SZ_WIN = (size_t)243*CHN*4;             //    62,208
    const size_t SZ_WQ  = (size_t)80*CHN*2;              //    10,240
    const size_t SZ_OP  = (size_t)BATCH*NRB*NQTR*2048*4; // 18,874,368
    const size_t SZ_LG  = (size_t)BATCH*NRB*NQTR*32*4;   //   294,912
    const size_t SZ_KI  = (size_t)8*KPAD*4;              //       512
    char* p = (char*)d_ws;
    float* FR      = (float*)p;           p += SZ_FR;
    short* FBI0raw = (short*)p;           p += SZ_FBI;
    short* FBI1raw = (short*)p;           p += SZ_FBI;
    short* Whi     = (short*)p;           p += SZ_WT;
    short* Wlo     = (short*)p;           p += SZ_WT;
    short* Qb16    = (short*)p;           p += SZ_QK;
    short* Kb16    = (short*)p;           p += SZ_QK;
    short* Vb16    = (short*)p;           p += SZ_VB;
    float* AT      = (float*)p;           p += SZ_AT;
    float* Wo      = (float*)p;           p += SZ_WO;
    float* Win     = (float*)p;           p += SZ_WIN;
    short* Wqh     = (short*)p;           p += SZ_WQ;
    short* Wql     = (short*)p;           p += SZ_WQ;
    float* Opg     = (float*)p;           p += SZ_OP;
    float* lgb     = (float*)p;           p += SZ_LG;
    float* Kinf    = (float*)p;           p += SZ_KI;
    short* FBI0 = FBI0raw + (size_t)GUARD*128;
    short* FBI1 = FBI1raw + (size_t)GUARD*128;
    float* outp = (float*)d_out;

    // FR memset dropped: every FR element read (conv3 mode-1 interior,
    // attn_fin interior) is written by k_conv_in first.
    hipMemsetAsync(FBI0raw, 0, SZ_FBI, stream);
    hipMemsetAsync(FBI1raw, 0, SZ_FBI, stream);
    hipMemsetAsync(AT, 0, SZ_AT, stream);
    hipMemsetAsync(Kinf, 0, SZ_KI, stream);

    dim3 blk(256);

    const int PREP_TOT = NBLK*2*9*CHN*CHN + 80*CHN + 81*CIN*CHN + 243*CHN;
    k_prep_all<<<(PREP_TOT + 255)/256, blk, 0, stream>>>(
        rw1, rw2, Whi, Wlo, wq, wk, wv, Wqh, Wql, w_out, Wo, w_in, Win);
    k_conv_in<<<BATCH*96*3*2, blk, 0, stream>>>(x, Win, b_in, a_in, FR, FBI0);
    for (int i = 0; i < NBLK; ++i) {
        k_conv3_mfma<<<BATCH*576, blk, 0, stream>>>(
            FBI0,
            Whi + (size_t)(2*i)*9*CHN*CHN, Wlo + (size_t)(2*i)*9*CHN*CHN,
            rb1 + i*CHN, ra + i, (float*)nullptr, FBI1, 0);
        k_conv3_mfma<<<BATCH*576, blk, 0, stream>>>(
            FBI1,
            Whi + (size_t)(2*i+1)*9*CHN*CHN, Wlo + (size_t)(2*i+1)*9*CHN*CHN,
            rb2 + i*CHN, ra + i, FR, FBI0, 1);
    }
    k_qkv_mfma<<<BATCH*NCHK, blk, 0, stream>>>(
        FBI0, Wqh, Wql, bq, bk, bv, Qb16, Kb16, Vb16, Kinf);
    k_attn_mfma<<<BATCH*NRB*NQTR, blk, 0, stream>>>(
        Qb16, Kb16, Vb16, Kinf, Opg, lgb);
    k_attn_fin<<<BATCH*NRB, blk, 0, stream>>>(Opg, lgb, FR, gamma, AT);
    k_conv_out<<<(BATCH*NSP)/16, blk, 0, stream>>>(AT, Wo, b_out, outp);
}

// Round 11
// 321.885 us; speedup vs baseline: 1.4463x; 1.0323x over previous
//
#include <hip/hip_runtime.h>
#include <cmath>

#define BATCH 2
#define CIN 3
#define HH 96
#define WW 96
#define NSP (HH*WW)      // 9216
#define CHN 64
#define C8 8
#define NBLK 5

#define PW 98            // padded width/height (3x3 convs)
#define PN (PW*PW)       // 9604 padded spatial
#define GUARD 128        // guard rows (spatial) each side of FBI buffers
#define FBST ((PN + 2*GUARD)*128)  // shorts per batch in FBI (hi|lo interleaved)

#define PW2 104          // padded width for 9x9 conv_out input
#define PN2 (PW2*PW2)    // 10816

#define NRB (NSP/32)     // 288 row-blocks in attention
#define NCHK 144         // 64-col j-chunks (9216/64)
#define NQTR 4           // j split across 4 blocks

#define KPAD 16          // Kinf padded stride (floats) -> 1 entry per 64B line

#define LOG2E 1.4426950408889634f
#define BOOST 100.0f     // exponent boost: p' = 2^(e-M+BOOST), overflow-safe

typedef __attribute__((ext_vector_type(8))) short bf16x8;
typedef __attribute__((ext_vector_type(4))) float f32x4;

static __device__ __forceinline__ short f2b(float f) {
    union { float f; unsigned u; } v; v.f = f;
    unsigned r = (v.u + 0x7FFFu + ((v.u >> 16) & 1u)) >> 16;
    return (short)r;
}
static __device__ __forceinline__ float b2f(short s) {
    union { unsigned u; float f; } v; v.u = ((unsigned)(unsigned short)s) << 16;
    return v.f;
}
static __device__ __forceinline__ void split2(float v, short& hi, short& lo) {
    hi = f2b(v);
    lo = f2b(v - b2f(hi));
}

// ---------------------------------------------------------------------------
// border zero: replaces 15.6MB of full-buffer memsets (FBI0/FBI1/AT) with
// ~1.2MB of targeted writes. Only the padding borders need zeros — every
// interior element is fully overwritten each launch (conv_in/conv3: FBI
// rows/cols 1..96, all 128 shorts; attn_fin: AT rows/cols 4..99, all 64 ch)
// and the GUARD regions are never read. Runs every launch, so workspace
// re-poisoning between iterations is still handled.
__global__ __launch_bounds__(256) void k_zero_border(
        short* __restrict__ FBI0, short* __restrict__ FBI1,
        float* __restrict__ AT) {
    int idx = blockIdx.x*256 + threadIdx.x;     // one 16B chunk per thread
    const int FBC = 2*2*388*16;                 // 24832
    if (idx < FBC) {
        int chunk = idx & 15;
        int r = idx >> 4;            // 0..1551
        int cell = r % 388;
        int bb = r / 388;            // buf*2 + batch
        int buf = bb >> 1, b = bb & 1;
        int pp;
        if (cell < 98)       pp = cell;                     // row 0
        else if (cell < 196) pp = 97*PW + (cell - 98);      // row 97
        else if (cell < 292) pp = (cell - 196 + 1)*PW;      // col 0, rows 1..96
        else                 pp = (cell - 292 + 1)*PW + 97; // col 97, rows 1..96
        short* base = (buf ? FBI1 : FBI0) + (size_t)b*FBST
                    + (size_t)pp*128 + chunk*8;
        *(float4*)base = make_float4(0.f, 0.f, 0.f, 0.f);
        return;
    }
    idx -= FBC;
    const int ATC = 2*1600*16;                  // 51200
    if (idx < ATC) {
        int chunk = idx & 15;
        int r = idx >> 4;            // 0..3199
        int cell = r % 1600;
        int b = r / 1600;
        int pp;
        if (cell < 416)      pp = cell;                     // rows 0..3
        else if (cell < 832) pp = 100*PW2 + (cell - 416);   // rows 100..103
        else {
            int c2 = cell - 832;     // 0..767
            int row = 4 + (c2 >> 3); // 4..99
            int col = c2 & 7;        // 0..3 -> left, 4..7 -> right
            pp = row*PW2 + (col < 4 ? col : col + 96);
        }
        float* base = AT + (size_t)b*PN2 + (size_t)pp*CHN + chunk*4;
        *(float4*)base = make_float4(0.f, 0.f, 0.f, 0.f);
    }
}

// ---------------------------------------------------------------------------
// merged weight prep. Conv3 + qkv weights in MFMA FRAGMENT ORDER (r8 win:
// contiguous 1KB weight loads instead of 128B-stride scatters, -133us).
__global__ __launch_bounds__(256) void k_prep_all(
        const float* __restrict__ rw1, const float* __restrict__ rw2,
        short* __restrict__ Whi, short* __restrict__ Wlo,
        const float* __restrict__ wq, const float* __restrict__ wk,
        const float* __restrict__ wv,
        short* __restrict__ Wqh, short* __restrict__ Wql,
        const float* __restrict__ w_out, float* __restrict__ Wo,
        const float* __restrict__ w_in, float* __restrict__ Win) {
    int idx = blockIdx.x * 256 + threadIdx.x;
    const int TOT_A = NBLK*2*9*CHN*CHN;   // 368640 = 10*9*4*2*64*8
    const int TOT_B = 80*CHN;             //   5120 = 5*2*64*8
    const int TOT_C = 81*CIN*CHN;         //  15552
    if (idx < TOT_A) {
        int e   = idx & 7;
        int l   = (idx >> 3) & 63;
        int cih = (idx >> 9) & 1;
        int ct  = (idx >> 10) & 3;
        int r2  = idx >> 12;              // 0..89
        int kyx = r2 % 9;
        int conv = r2 / 9;
        int blk = conv >> 1, s = conv & 1;
        int co = ct*16 + (l & 15);
        int ci = cih*32 + ((l >> 4) << 3) + e;
        const float* src = s ? rw2 : rw1;
        float v = src[(((size_t)(blk*CHN + co))*CHN + ci)*9 + kyx];
        short h, lo; split2(v, h, lo);
        Whi[idx] = h; Wlo[idx] = lo;
        return;
    }
    idx -= TOT_A;
    if (idx < TOT_B) {
        int e   = idx & 7;
        int l   = (idx >> 3) & 63;
        int cih = (idx >> 9) & 1;
        int ct  = idx >> 10;              // 0..4
        int co = ct*16 + (l & 15);
        int ci = cih*32 + ((l >> 4) << 3) + e;
        float v;
        if (co < 8)       v = wq[co*CHN + ci];
        else if (co < 16) v = wk[(co-8)*CHN + ci];
        else              v = wv[(co-16)*CHN + ci];
        short h, lo; split2(v, h, lo);
        Wqh[idx] = h; Wql[idx] = lo;
        return;
    }
    idx -= TOT_B;
    if (idx < TOT_C) {
        int ci = idx & 63;
        int co = (idx >> 6) % 3;
        int kyx = idx / 192;
        Wo[idx] = w_out[((size_t)(co*CHN + ci))*81 + kyx];
        return;
    }
    idx -= TOT_C;
    if (idx < 243*CHN) {
        int co = idx & 63;
        int k  = idx >> 6;          // 0..242
        int ci = k / 81, kk = k % 81;
        Win[idx] = w_in[((size_t)(co*CIN + ci))*81 + kk];
    }
}

// ---------------------------------------------------------------------------
// conv 9x9 (3 -> 64), pad 4, + PReLU. x window staged once in LDS.
// XCD-swizzled (y-slab per XCD, matches conv3's mapping).
__global__ __launch_bounds__(256) void k_conv_in(const float* __restrict__ x,
        const float* __restrict__ Win, const float* __restrict__ bias,
        const float* __restrict__ a, float* __restrict__ FR,
        short* __restrict__ FBI) {
    __shared__ float xw[3*9*40];     // [ci][ky][c], c = xs-(x0-4), 4320 B
    int t = threadIdx.x;
    int blk = blockIdx.x;
    int xcd = blk & 7;
    int l   = blk >> 3;              // 0..143 = b(2) x y%12(12) x s(6)
    int b   = l / 72;
    int r   = l % 72;
    int y   = xcd*12 + r/6;
    int s   = r % 6;                 // xc*2 + coh
    int xc  = s >> 1;
    int coh = s & 1;
    int x0 = xc*32;
    int px  = t & 31;
    int cog = t >> 5;                // 8 groups x 4 co (within this half)

    // ---- stage x window: rows y-4..y+4, cols x0-4..x0+35, 3 ci ----
    #pragma unroll
    for (int u = 0; u < 5; ++u) {
        int idx = u*256 + t;
        if (idx < 1080) {
            int ci = idx / 360;
            int rr = idx - ci*360;
            int ky = rr / 40;
            int c  = rr - ky*40;
            int yy = y + ky - 4;
            int xs = x0 + c - 4;
            float v = 0.f;
            if (yy >= 0 && yy < 96 && xs >= 0 && xs < 96)
                v = x[((size_t)(b*CIN + ci))*NSP + yy*96 + xs];
            xw[idx] = v;
        }
    }
    __syncthreads();

    int cbase = coh*32 + cog*4;
    float acc[4];
    #pragma unroll
    for (int rr = 0; rr < 4; ++rr) acc[rr] = bias[cbase + rr];

    #pragma unroll 1
    for (int ci = 0; ci < CIN; ++ci) {
        #pragma unroll 1
        for (int ky = 0; ky < 9; ++ky) {
            const float* xrow = xw + (ci*9 + ky)*40 + px;
            const float* wrow = Win + (size_t)(ci*81 + ky*9)*64 + cbase;
            float xv[9];
            #pragma unroll
            for (int kx = 0; kx < 9; ++kx) xv[kx] = xrow[kx];
            #pragma unroll
            for (int kx = 0; kx < 9; ++kx) {
                float4 wv = *(const float4*)(wrow + kx*64);
                acc[0] = fmaf(xv[kx], wv.x, acc[0]);
                acc[1] = fmaf(xv[kx], wv.y, acc[1]);
                acc[2] = fmaf(xv[kx], wv.z, acc[2]);
                acc[3] = fmaf(xv[kx], wv.w, acc[3]);
            }
        }
    }
    float sl = a[0];
    #pragma unroll
    for (int rr = 0; rr < 4; ++rr) {
        float v = acc[rr];
        acc[rr] = v >= 0.f ? v : sl*v;
    }
    int np = (y + 1)*PW + x0 + px + 1;
    float* fr = FR + ((size_t)b*PN + np)*CHN + cbase;
    *(float4*)fr = make_float4(acc[0], acc[1], acc[2], acc[3]);
    union { short ss[4]; short4 v4; } h4, l4;
    #pragma unroll
    for (int rr = 0; rr < 4; ++rr) split2(acc[rr], h4.ss[rr], l4.ss[rr]);
    short* fo = FBI + (size_t)b*FBST + (size_t)np*128 + cbase;
    *(short4*)fo        = h4.v4;
    *(short4*)(fo + 64) = l4.v4;
}

// ---------------------------------------------------------------------------
// 3x3 conv 64->64, implicit GEMM, split-bf16 3-MFMA, XCD-swizzled.
// Weight loads FRAGMENT-ORDER CONTIGUOUS (base + lane*16B = 1KB/inst).
__global__ __launch_bounds__(256, 4) void k_conv3_mfma(
        const short* __restrict__ FBin,
        const short* __restrict__ Whi, const short* __restrict__ Wlo,
        const float* __restrict__ bias, const float* __restrict__ slope_p,
        float* __restrict__ FR, short* __restrict__ FBout, int mode) {
    __shared__ short xs[3*18*128];   // 13,824 B
    char* xb = (char*)xs;
    int t = threadIdx.x;
    int w = t >> 6, lane = t & 63;
    int q = lane >> 4, n16 = lane & 15;
    int blk = blockIdx.x;
    int xcd = blk & 7;
    int l   = blk >> 3;              // 0..143 = b(2) x y%12(12) x xchunk(6)
    int b   = l / 72;
    int rem = l % 72;
    int y   = xcd*12 + rem/6;
    int x0  = (rem % 6)*16;

    const short* fbB = FBin + (size_t)b*FBST;

    // ---- stage: 864 16-B granules, swizzled into LDS ----
    #pragma unroll
    for (int k = 0; k < 4; ++k) {
        int u = k*256 + t;
        if (u < 864) {
            int px_lin = u >> 4, G = u & 15;
            int r = px_lin / 18, p = px_lin - r*18;
            const float4 src = *(const float4*)(fbB
                + ((size_t)((y + r)*PW + x0 + p))*128 + G*8);
            *(float4*)(xb + (px_lin << 8) + ((G ^ (px_lin & 15)) << 4)) = src;
        }
    }
    __syncthreads();

    // ---- compute: wave = 16 px x 16 co (ct = w) ----
    int ct = w;
    f32x4 acc = {0,0,0,0};

    #pragma unroll
    for (int dy = 0; dy < 3; ++dy) {
        #pragma unroll
        for (int dx = 0; dx < 3; ++dx) {
            int kyx = dy*3 + dx;
            int px_lin = dy*18 + n16 + dx;
            int pbase = px_lin << 8;
            int sw = px_lin & 15;
            #pragma unroll
            for (int cih = 0; cih < 2; ++cih) {
                int Gh = cih*4 + q;
                int Gl = 8 + cih*4 + q;
                bf16x8 bhi = *(const bf16x8*)(xb + pbase + ((Gh ^ sw) << 4));
                bf16x8 blo = *(const bf16x8*)(xb + pbase + ((Gl ^ sw) << 4));
                size_t woff = ((size_t)((kyx*4 + ct)*2 + cih)*64 + lane)*8;
                bf16x8 ahi = *(const bf16x8*)(Whi + woff);
                bf16x8 alo = *(const bf16x8*)(Wlo + woff);
                acc = __builtin_amdgcn_mfma_f32_16x16x32_bf16(ahi, bhi, acc, 0, 0, 0);
                acc = __builtin_amdgcn_mfma_f32_16x16x32_bf16(ahi, blo, acc, 0, 0, 0);
                acc = __builtin_amdgcn_mfma_f32_16x16x32_bf16(alo, bhi, acc, 0, 0, 0);
            }
        }
    }

    // ---- epilogue: all outputs interior, vectorized stores ----
    int nb = (y + 1)*PW + x0 + 1 + n16;
    float sl = slope_p[0];
    short* fbo = FBout + (size_t)b*FBST + (size_t)nb*128;
    int co0 = ct*16 + q*4;
    float v[4];
    #pragma unroll
    for (int r = 0; r < 4; ++r) v[r] = acc[r] + bias[co0 + r];
    if (mode == 0) {
        #pragma unroll
        for (int r = 0; r < 4; ++r) v[r] = v[r] >= 0.f ? v[r] : sl*v[r];
    } else {
        float* fr = FR + ((size_t)b*PN + nb)*CHN + co0;
        float4 f = *(const float4*)fr;
        v[0] += f.x; v[1] += f.y; v[2] += f.z; v[3] += f.w;
        *(float4*)fr = make_float4(v[0], v[1], v[2], v[3]);
    }
    union { short s[4]; short4 v4; } h4, l4;
    #pragma unroll
    for (int r = 0; r < 4; ++r) split2(v[r], h4.s[r], l4.s[r]);
    *(short4*)(fbo + co0)      = h4.v4;
    *(short4*)(fbo + 64 + co0) = l4.v4;
}

// ---------------------------------------------------------------------------
// qkv projection as 1x1-conv implicit GEMM. N-space aligned blocks
// (coalesced V fragment stores). Weight loads fragment-order contiguous.
__global__ __launch_bounds__(256) void k_qkv_mfma(
        const short* __restrict__ FBin,
        const short* __restrict__ Wh, const short* __restrict__ Wl,
        const float* __restrict__ bq, const float* __restrict__ bk,
        const float* __restrict__ bv,
        short* __restrict__ Qb, short* __restrict__ Kb, short* __restrict__ Vb,
        float* __restrict__ Kinf) {
    __shared__ float kls[4][8];
    int t = threadIdx.x;
    int w = t >> 6, lane = t & 63;
    int q = lane >> 4, n16 = lane & 15;
    int blk = blockIdx.x;
    int b = blk / NCHK, chunk = blk % NCHK;
    int n  = chunk*64 + w*16 + n16;          // 0..9215, always valid
    int iy = n / WW, ix = n - iy*WW;
    int nb = (iy + 1)*PW + ix + 1;

    const short* fb = FBin + (size_t)b*FBST;
    f32x4 acc[5] = {{0,0,0,0},{0,0,0,0},{0,0,0,0},{0,0,0,0},{0,0,0,0}};

    int nbase = nb*128;
    #pragma unroll
    for (int cih = 0; cih < 2; ++cih) {
        bf16x8 bhi = *(const bf16x8*)(fb + nbase + cih*32 + q*8);
        bf16x8 blo = *(const bf16x8*)(fb + nbase + 64 + cih*32 + q*8);
        #pragma unroll
        for (int ct = 0; ct < 5; ++ct) {
            size_t aoff = ((size_t)(ct*2 + cih)*64 + lane)*8;
            bf16x8 ahi = *(const bf16x8*)(Wh + aoff);
            bf16x8 alo = *(const bf16x8*)(Wl + aoff);
            acc[ct] = __builtin_amdgcn_mfma_f32_16x16x32_bf16(ahi, bhi, acc[ct], 0, 0, 0);
            acc[ct] = __builtin_amdgcn_mfma_f32_16x16x32_bf16(ahi, blo, acc[ct], 0, 0, 0);
            acc[ct] = __builtin_amdgcn_mfma_f32_16x16x32_bf16(alo, bhi, acc[ct], 0, 0, 0);
        }
    }

    int jin = w*16 + n16;                    // j within chunk, wave-local
    float kabs[4] = {0.f, 0.f, 0.f, 0.f};
    union { short s[4]; short4 v4; } pk;
    if (q < 2) {
        #pragma unroll
        for (int r = 0; r < 4; ++r)
            pk.s[r] = f2b((acc[0][r] + bq[q*4 + r]) * LOG2E);
        *(short4*)(Qb + ((size_t)b*NSP + n)*8 + q*4) = pk.v4;
    } else {
        // K fragment coords (inverse of attn's jrow mapping)
        int ttk  = ((jin >> 5) << 1) | ((jin >> 2) & 1);
        int n16k = (((jin >> 3) & 3) << 2) | (jin & 3);
        size_t kbase = (((size_t)(b*NCHK + chunk)*4 + ttk)*16 + n16k)*8;
        #pragma unroll
        for (int r = 0; r < 4; ++r) {
            float kv = acc[0][r] + bk[(q - 2)*4 + r];
            kabs[r] = fabsf(kv) * 1.01f;
            pk.s[r] = f2b(kv);
        }
        *(short4*)(Kb + kbase + (q - 2)*4) = pk.v4;
    }
    // V fragment coords (j = ks*32 + quad*8 + e within chunk)
    int ksv = jin >> 5, qv = (jin >> 3) & 3, ev = jin & 7;
    size_t vbase = ((size_t)(b*NCHK + chunk)*2 + ksv)*2048 + qv*128 + ev;
    #pragma unroll
    for (int ct = 1; ct < 5; ++ct) {
        #pragma unroll
        for (int r = 0; r < 4; ++r) {
            int co = ct*16 + q*4 + r;
            Vb[vbase + (size_t)(ct - 1)*512 + (q*4 + r)*8] =
                f2b(acc[ct][r] + bv[co - 16]);
        }
    }
    #pragma unroll
    for (int r = 0; r < 4; ++r) {
        #pragma unroll
        for (int off = 1; off < 16; off <<= 1)
            kabs[r] = fmaxf(kabs[r], __shfl_xor(kabs[r], off));
    }
    if (q >= 2 && n16 == 0) {
        #pragma unroll
        for (int r = 0; r < 4; ++r)
            kls[w][(q - 2)*4 + r] = kabs[r];
    }
    __syncthreads();
    if (t < 8) {
        float m = fmaxf(fmaxf(kls[0][t], kls[1][t]),
                        fmaxf(kls[2][t], kls[3][t]));
        atomicMax((int*)&Kinf[t*KPAD], __float_as_int(m));
    }
}

// ---------------------------------------------------------------------------
// chunk buffer for attention (single-buffered: TLP beats ILP here — both
// the full dbuf (r2) and K-prefetch (r6) variants lost to occupancy).
struct CB { bf16x8 kf[4]; bf16x8 vf[8]; };

static __device__ __forceinline__ void attn_load(CB& cb,
        const short* __restrict__ KpJ, const short* __restrict__ VpJ,
        int n16, int lane) {
    #pragma unroll
    for (int tt = 0; tt < 4; ++tt)
        cb.kf[tt] = *(const bf16x8*)(KpJ + tt*128 + n16*8);
    #pragma unroll
    for (int ks = 0; ks < 2; ++ks)
        #pragma unroll
        for (int ct = 0; ct < 4; ++ct)
            cb.vf[ks*4 + ct] = *(const bf16x8*)(VpJ + (ks*4 + ct)*512 + lane*8);
}

static __device__ __forceinline__ void attn_compute(const CB& cb,
        const bf16x8 (&qf)[2], const f32x4 (&ci)[2],
        f32x4 (&accO)[2][4], float (&lp)[2]) {
    union PB { int di[8]; bf16x8 v8[2]; };
    PB pb[2];
    #pragma unroll
    for (int rg = 0; rg < 2; ++rg) {
        f32x4 e[4];
        #pragma unroll
        for (int tt = 0; tt < 4; ++tt)
            e[tt] = __builtin_amdgcn_mfma_f32_16x16x32_bf16(
                cb.kf[tt], qf[rg], ci[rg], 0, 0, 0);
        float st[4];
        #pragma unroll
        for (int tt = 0; tt < 4; ++tt) {
            #pragma unroll
            for (int r = 0; r < 4; ++r)
                e[tt][r] = __builtin_amdgcn_exp2f(e[tt][r]);
            st[tt] = (e[tt][0] + e[tt][1]) + (e[tt][2] + e[tt][3]);
        }
        lp[rg] += (st[0] + st[1]) + (st[2] + st[3]);
        // pack P to bf16 fragments eagerly (frees the 16 f32 e regs)
        #pragma unroll
        for (int tt = 0; tt < 4; ++tt) {
            pb[rg].di[tt*2]   = __builtin_amdgcn_perm(__float_as_uint(e[tt][1]),
                                             __float_as_uint(e[tt][0]), 0x07060302u);
            pb[rg].di[tt*2+1] = __builtin_amdgcn_perm(__float_as_uint(e[tt][3]),
                                             __float_as_uint(e[tt][2]), 0x07060302u);
        }
    }
    #pragma unroll
    for (int ks = 0; ks < 2; ++ks)
        #pragma unroll
        for (int rg = 0; rg < 2; ++rg)
            #pragma unroll
            for (int ct = 0; ct < 4; ++ct)
                accO[rg][ct] = __builtin_amdgcn_mfma_f32_16x16x32_bf16(
                    pb[rg].v8[ks], cb.vf[ks*4 + ct], accO[rg][ct], 0, 0, 0);
}

// MFMA flash attention, bound-based softmax, j split across 4 blocks.
__global__ __launch_bounds__(256) void k_attn_mfma(
        const short* __restrict__ Qb, const short* __restrict__ Kb,
        const short* __restrict__ Vb, const float* __restrict__ Kinf_p,
        float* __restrict__ Opg, float* __restrict__ lg) {
    __shared__ float Opart[4][16][68];
    __shared__ float lsh[4][2][16];

    int blk = blockIdx.x;
    int b    = blk / (NRB*NQTR);
    int rem  = blk % (NRB*NQTR);
    int rb   = rem / NQTR;
    int qtr  = rem % NQTR;
    int i0 = rb*32;
    int t = threadIdx.x;
    int w = t >> 6;
    int lane = t & 63;
    int quad = lane >> 4, n16 = lane & 15;

    const short* Qp = Qb + ((size_t)b*NSP)*8;
    const short* Kp = Kb + ((size_t)b*NSP)*8;
    const short* Vp = Vb + ((size_t)b*CHN)*NSP;

    bf16x8 qf[2];
    float Mi[2];
    #pragma unroll
    for (int rg = 0; rg < 2; ++rg) {
        bf16x8 z = {0,0,0,0,0,0,0,0};
        qf[rg] = z;
        if (quad == 0)
            qf[rg] = *(const bf16x8*)(Qp + (size_t)(i0 + rg*16 + n16)*8);
        float s1 = 0.f;
        #pragma unroll
        for (int c = 0; c < 8; ++c)
            s1 += fabsf(b2f(qf[rg][c])) * Kinf_p[c*KPAD];
        float Mv = s1 + 1.0f - BOOST;
        Mi[rg] = __shfl(Mv, n16);
    }

    f32x4 accO[2][4] = {{{0,0,0,0},{0,0,0,0},{0,0,0,0},{0,0,0,0}},
                        {{0,0,0,0},{0,0,0,0},{0,0,0,0},{0,0,0,0}}};
    float lp[2] = {0.f, 0.f};
    f32x4 ci[2];
    #pragma unroll
    for (int rg = 0; rg < 2; ++rg) {
        ci[rg][0] = -Mi[rg]; ci[rg][1] = -Mi[rg];
        ci[rg][2] = -Mi[rg]; ci[rg][3] = -Mi[rg];
    }

    // wave w covers 9 chunks of 64 j within its quarter
    int Jb = qtr*36 + w*9;
    const short* KpJ = Kp + (size_t)Jb*512;
    const short* VpJ = Vp + (size_t)Jb*4096;

    #pragma unroll 1
    for (int jc = 0; jc < 9; ++jc) {
        CB cb;
        attn_load(cb, KpJ, VpJ, n16, lane);
        attn_compute(cb, qf, ci, accO, lp);
        KpJ += 512;
        VpJ += 4096;
    }

    // ---- epilogue: cross-wave reduce, rg-looped to halve LDS ----
    #pragma unroll
    for (int rg = 0; rg < 2; ++rg) {
        float l = lp[rg];
        l += __shfl_xor(l, 16);
        l += __shfl_xor(l, 32);
        if (quad == 0) lsh[w][rg][n16] = l;
    }

    size_t obase = (((size_t)(b*NRB + rb))*NQTR + qtr)*2048;
    int row16 = t >> 4;          // 0..15
    int c0 = (t & 15)*4;
    #pragma unroll
    for (int rg = 0; rg < 2; ++rg) {
        if (rg) __syncthreads();
        #pragma unroll
        for (int ct = 0; ct < 4; ++ct)
            #pragma unroll
            for (int r = 0; r < 4; ++r)
                Opart[w][quad*4 + r][ct*16 + n16] = accO[rg][ct][r];
        __syncthreads();
        #pragma unroll
        for (int cc = 0; cc < 4; ++cc) {
            int c = c0 + cc;
            Opg[obase + (size_t)(rg*16 + row16)*64 + c] =
                Opart[0][row16][c] + Opart[1][row16][c]
              + Opart[2][row16][c] + Opart[3][row16][c];
        }
    }
    if (t < 32) {
        int rgl = t >> 4, ii = t & 15;
        lg[(((size_t)(b*NRB + rb))*NQTR + qtr)*32 + t] =
            lsh[0][rgl][ii] + lsh[1][rgl][ii]
          + lsh[2][rgl][ii] + lsh[3][rgl][ii];
    }
}

// ---------------------------------------------------------------------------
// attention finalize: merge j-quarters, normalize, add residual, write AT.
__global__ __launch_bounds__(256) void k_attn_fin(
        const float* __restrict__ Opg, const float* __restrict__ lg,
        const float* __restrict__ FR, const float* __restrict__ gamma_p,
        float* __restrict__ AT) {
    int blk = blockIdx.x;            // b*NRB + rb
    int b = blk / NRB, rb = blk % NRB;
    int t = threadIdx.x;
    int row = t >> 3;
    int c0 = (t & 7)*8;
    float g = gamma_p[0];
    size_t ob = ((size_t)blk*NQTR)*2048 + (size_t)row*64;
    float l = 0.f;
    #pragma unroll
    for (int k = 0; k < NQTR; ++k)
        l += lg[((size_t)blk*NQTR + k)*32 + row];
    float inv = g / fmaxf(l, 1e-35f);
    int gi = rb*32 + row;
    int iy = gi / WW, ix = gi - iy*WW;
    size_t frb = ((size_t)b*PN + (iy + 1)*PW + ix + 1)*CHN;
    size_t atb = ((size_t)b*PN2 + (iy + 4)*PW2 + ix + 4)*CHN;
    #pragma unroll
    for (int cc = 0; cc < 8; ++cc) {
        int c = c0 + cc;
        float Ov = 0.f;
        #pragma unroll
        for (int k = 0; k < NQTR; ++k)
            Ov += Opg[ob + (size_t)k*2048 + c];
        AT[atb + c] = Ov*inv + FR[frb + c];
    }
}

// ---------------------------------------------------------------------------
// conv 9x9 (64 -> 3) + tanh. Wave per 4 pixels, lane = ci.
__global__ __launch_bounds__(256) void k_conv_out(const float* __restrict__ AT,
        const float* __restrict__ Wo, const float* __restrict__ bias,
        float* __restrict__ out) {
    int t = threadIdx.x;
    int w = t >> 6, lane = t & 63;
    int base = blockIdx.x*16 + w*4;
    int b = base / NSP;
    int n0 = base % NSP;
    int y0 = n0 / WW, x0 = n0 % WW;

    float s[4][3] = {{0,0,0},{0,0,0},{0,0,0},{0,0,0}};
    for (int ky = 0; ky < 9; ++ky) {
        const float* arow = AT + ((size_t)b*PN2 + (size_t)(y0 + ky)*PW2 + x0)*CHN + lane;
        const float* wrow = Wo + (size_t)ky*9*192;
        float xv[12];
        #pragma unroll
        for (int u = 0; u < 12; ++u)
            xv[u] = arow[(size_t)u*CHN];
        #pragma unroll
        for (int kx = 0; kx < 9; ++kx) {
            float w0 = wrow[kx*192 +   0 + lane];
            float w1 = wrow[kx*192 +  64 + lane];
            float w2 = wrow[kx*192 + 128 + lane];
            #pragma unroll
            for (int p = 0; p < 4; ++p) {
                float x = xv[kx + p];
                s[p][0] = fmaf(x, w0, s[p][0]);
                s[p][1] = fmaf(x, w1, s[p][1]);
                s[p][2] = fmaf(x, w2, s[p][2]);
            }
        }
    }
    #pragma unroll
    for (int p = 0; p < 4; ++p)
        #pragma unroll
        for (int c = 0; c < 3; ++c) {
            float v = s[p][c];
            v += __shfl_xor(v, 1);
            v += __shfl_xor(v, 2);
            v += __shfl_xor(v, 4);
            v += __shfl_xor(v, 8);
            v += __shfl_xor(v, 16);
            v += __shfl_xor(v, 32);
            s[p][c] = v;
        }
    #pragma unroll
    for (int p = 0; p < 4; ++p)
        #pragma unroll
        for (int c = 0; c < 3; ++c)
            if (lane == p*3 + c)
                out[((size_t)(b*3 + c))*NSP + n0 + p] = tanhf(s[p][c] + bias[c]);
}

// ---------------------------------------------------------------------------
extern "C" void kernel_launch(void* const* d_in, const int* in_sizes, int n_in,
                              void* d_out, int out_size, void* d_ws, size_t ws_size,
                              hipStream_t stream) {
    (void)in_sizes; (void)n_in; (void)out_size; (void)ws_size;
    const float* x     = (const float*)d_in[0];
    const float* w_in  = (const float*)d_in[1];
    const float* b_in  = (const float*)d_in[2];
    const float* a_in  = (const float*)d_in[3];
    const float* rw1   = (const float*)d_in[4];
    const float* rb1   = (const float*)d_in[5];
    const float* ra    = (const float*)d_in[6];
    const float* rw2   = (const float*)d_in[7];
    const float* rb2   = (const float*)d_in[8];
    const float* wq    = (const float*)d_in[9];
    const float* bq    = (const float*)d_in[10];
    const float* wk    = (const float*)d_in[11];
    const float* bk    = (const float*)d_in[12];
    const float* wv    = (const float*)d_in[13];
    const float* bv    = (const float*)d_in[14];
    const float* gamma = (const float*)d_in[15];
    const float* w_out = (const float*)d_in[16];
    const float* b_out = (const float*)d_in[17];

    const size_t SZ_FR  = (size_t)BATCH*PN*CHN*4;        // 4,917,248
    const size_t SZ_FBI = (size_t)BATCH*FBST*2;          // 5,048,320
    const size_t SZ_WT  = (size_t)NBLK*2*9*CHN*CHN*2;    //   737,280
    const size_t SZ_QK  = (size_t)BATCH*NSP*C8*2;        //   294,912
    const size_t SZ_VB  = (size_t)BATCH*CHN*NSP*2;       // 2,359,296
    const size_t SZ_AT  = (size_t)BATCH*PN2*CHN*4;       // 5,537,792
    const size_t SZ_WO  = (size_t)81*CIN*CHN*4;          //    62,208
    const size_t SZ_WIN = (size_t)243*CHN*4;             //    62,208
    const size_t SZ_WQ  = (size_t)80*CHN*2;              //    10,240
    const size_t SZ_OP  = (size_t)BATCH*NRB*NQTR*2048*4; // 18,874,368
    const size_t SZ_LG  = (size_t)BATCH*NRB*NQTR*32*4;   //   294,912
    const size_t SZ_KI  = (size_t)8*KPAD*4;              //       512
    char* p = (char*)d_ws;
    float* FR      = (float*)p;           p += SZ_FR;
    short* FBI0raw = (short*)p;           p += SZ_FBI;
    short* FBI1raw = (short*)p;           p += SZ_FBI;
    short* Whi     = (short*)p;           p += SZ_WT;
    short* Wlo     = (short*)p;           p += SZ_WT;
    short* Qb16    = (short*)p;           p += SZ_QK;
    short* Kb16    = (short*)p;           p += SZ_QK;
    short* Vb16    = (short*)p;           p += SZ_VB;
    float* AT      = (float*)p;           p += SZ_AT;
    float* Wo      = (float*)p;           p += SZ_WO;
    float* Win     = (float*)p;           p += SZ_WIN;
    short* Wqh     = (short*)p;           p += SZ_WQ;
    short* Wql     = (short*)p;           p += SZ_WQ;
    float* Opg     = (float*)p;           p += SZ_OP;
    float* lgb     = (float*)p;           p += SZ_LG;
    float* Kinf    = (float*)p;           p += SZ_KI;
    short* FBI0 = FBI0raw + (size_t)GUARD*128;
    short* FBI1 = FBI1raw + (size_t)GUARD*128;
    float* outp = (float*)d_out;

    hipMemsetAsync(Kinf, 0, SZ_KI, stream);

    dim3 blk(256);

    // borders only (interior fully overwritten each launch; guards unread)
    const int ZB_TOT = 2*2*388*16 + 2*1600*16;   // 76032
    k_zero_border<<<(ZB_TOT + 255)/256, blk, 0, stream>>>(FBI0, FBI1, AT);

    const int PREP_TOT = NBLK*2*9*CHN*CHN + 80*CHN + 81*CIN*CHN + 243*CHN;
    k_prep_all<<<(PREP_TOT + 255)/256, blk, 0, stream>>>(
        rw1, rw2, Whi, Wlo, wq, wk, wv, Wqh, Wql, w_out, Wo, w_in, Win);
    k_conv_in<<<BATCH*96*3*2, blk, 0, stream>>>(x, Win, b_in, a_in, FR, FBI0);
    for (int i = 0; i < NBLK; ++i) {
        k_conv3_mfma<<<BATCH*576, blk, 0, stream>>>(
            FBI0,
            Whi + (size_t)(2*i)*9*CHN*CHN, Wlo + (size_t)(2*i)*9*CHN*CHN,
            rb1 + i*CHN, ra + i, (float*)nullptr, FBI1, 0);
        k_conv3_mfma<<<BATCH*576, blk, 0, stream>>>(
            FBI1,
            Whi + (size_t)(2*i+1)*9*CHN*CHN, Wlo + (size_t)(2*i+1)*9*CHN*CHN,
            rb2 + i*CHN, ra + i, FR, FBI0, 1);
    }
    k_qkv_mfma<<<BATCH*NCHK, blk, 0, stream>>>(
        FBI0, Wqh, Wql, bq, bk, bv, Qb16, Kb16, Vb16, Kinf);
    k_attn_mfma<<<BATCH*NRB*NQTR, blk, 0, stream>>>(
        Qb16, Kb16, Vb16, Kinf, Opg, lgb);
    k_attn_fin<<<BATCH*NRB, blk, 0, stream>>>(Opg, lgb, FR, gamma, AT);
    k_conv_out<<<(BATCH*NSP)/16, blk, 0, stream>>>(AT, Wo, b_out, outp);
}

// Round 13
// 320.400 us; speedup vs baseline: 1.4530x; 1.0046x over previous
//
#include <hip/hip_runtime.h>
#include <cmath>

#define BATCH 2
#define CIN 3
#define HH 96
#define WW 96
#define NSP (HH*WW)      // 9216
#define CHN 64
#define C8 8
#define NBLK 5

#define PW 98            // padded width/height (3x3 convs)
#define PN (PW*PW)       // 9604 padded spatial
#define GUARD 128        // guard rows (spatial) each side of FBI buffers
#define FBST ((PN + 2*GUARD)*128)  // shorts per batch in FBI (hi|lo interleaved)

#define PW2 104          // padded width for 9x9 conv_out input
#define PN2 (PW2*PW2)    // 10816

#define NRB (NSP/32)     // 288 row-blocks in attention
#define NCHK 144         // 64-col j-chunks (9216/64)
#define NQTR 4           // j split across 4 blocks

#define KPAD 16          // Kinf padded stride (floats) -> 1 entry per 64B line

#define LOG2E 1.4426950408889634f
#define BOOST 100.0f     // exponent boost: p' = 2^(e-M+BOOST), overflow-safe

typedef __attribute__((ext_vector_type(8))) short bf16x8;
typedef __attribute__((ext_vector_type(4))) float f32x4;

static __device__ __forceinline__ short f2b(float f) {
    union { float f; unsigned u; } v; v.f = f;
    unsigned r = (v.u + 0x7FFFu + ((v.u >> 16) & 1u)) >> 16;
    return (short)r;
}
static __device__ __forceinline__ float b2f(short s) {
    union { unsigned u; float f; } v; v.u = ((unsigned)(unsigned short)s) << 16;
    return v.f;
}
static __device__ __forceinline__ void split2(float v, short& hi, short& lo) {
    hi = f2b(v);
    lo = f2b(v - b2f(hi));
}

// ---------------------------------------------------------------------------
// merged weight prep + border zero (one launch; all ranges independent).
// Conv3 + qkv weights in MFMA FRAGMENT ORDER (r8 win: contiguous 1KB weight
// loads instead of 128B-stride scatters, -133us). Border ranges zero only
// the padding cells (interior fully overwritten each launch; GUARD unread)
// — r11 win, -10us vs full memsets. Runs every launch (re-poison safe).
__global__ __launch_bounds__(256) void k_prep_all(
        const float* __restrict__ rw1, const float* __restrict__ rw2,
        short* __restrict__ Whi, short* __restrict__ Wlo,
        const float* __restrict__ wq, const float* __restrict__ wk,
        const float* __restrict__ wv,
        short* __restrict__ Wqh, short* __restrict__ Wql,
        const float* __restrict__ w_out, float* __restrict__ Wo,
        const float* __restrict__ w_in, float* __restrict__ Win,
        short* __restrict__ FBI0, short* __restrict__ FBI1,
        float* __restrict__ AT) {
    int idx = blockIdx.x * 256 + threadIdx.x;
    const int TOT_A = NBLK*2*9*CHN*CHN;   // 368640 = 10*9*4*2*64*8
    const int TOT_B = 80*CHN;             //   5120 = 5*2*64*8
    const int TOT_C = 81*CIN*CHN;         //  15552
    const int TOT_D = 243*CHN;            //  15552
    if (idx < TOT_A) {
        int e   = idx & 7;
        int l   = (idx >> 3) & 63;
        int cih = (idx >> 9) & 1;
        int ct  = (idx >> 10) & 3;
        int r2  = idx >> 12;              // 0..89
        int kyx = r2 % 9;
        int conv = r2 / 9;
        int blk = conv >> 1, s = conv & 1;
        int co = ct*16 + (l & 15);
        int ci = cih*32 + ((l >> 4) << 3) + e;
        const float* src = s ? rw2 : rw1;
        float v = src[(((size_t)(blk*CHN + co))*CHN + ci)*9 + kyx];
        short h, lo; split2(v, h, lo);
        Whi[idx] = h; Wlo[idx] = lo;
        return;
    }
    idx -= TOT_A;
    if (idx < TOT_B) {
        int e   = idx & 7;
        int l   = (idx >> 3) & 63;
        int cih = (idx >> 9) & 1;
        int ct  = idx >> 10;              // 0..4
        int co = ct*16 + (l & 15);
        int ci = cih*32 + ((l >> 4) << 3) + e;
        float v;
        if (co < 8)       v = wq[co*CHN + ci];
        else if (co < 16) v = wk[(co-8)*CHN + ci];
        else              v = wv[(co-16)*CHN + ci];
        short h, lo; split2(v, h, lo);
        Wqh[idx] = h; Wql[idx] = lo;
        return;
    }
    idx -= TOT_B;
    if (idx < TOT_C) {
        int ci = idx & 63;
        int co = (idx >> 6) % 3;
        int kyx = idx / 192;
        Wo[idx] = w_out[((size_t)(co*CHN + ci))*81 + kyx];
        return;
    }
    idx -= TOT_C;
    if (idx < TOT_D) {
        int co = idx & 63;
        int k  = idx >> 6;          // 0..242
        int ci = k / 81, kk = k % 81;
        Win[idx] = w_in[((size_t)(co*CIN + ci))*81 + kk];
        return;
    }
    idx -= TOT_D;
    const int FBC = 2*2*388*16;                 // 24832
    if (idx < FBC) {
        int chunk = idx & 15;
        int r = idx >> 4;            // 0..1551
        int cell = r % 388;
        int bb = r / 388;            // buf*2 + batch
        int buf = bb >> 1, b = bb & 1;
        int pp;
        if (cell < 98)       pp = cell;                     // row 0
        else if (cell < 196) pp = 97*PW + (cell - 98);      // row 97
        else if (cell < 292) pp = (cell - 196 + 1)*PW;      // col 0, rows 1..96
        else                 pp = (cell - 292 + 1)*PW + 97; // col 97, rows 1..96
        short* base = (buf ? FBI1 : FBI0) + (size_t)b*FBST
                    + (size_t)pp*128 + chunk*8;
        *(float4*)base = make_float4(0.f, 0.f, 0.f, 0.f);
        return;
    }
    idx -= FBC;
    const int ATC = 2*1600*16;                  // 51200
    if (idx < ATC) {
        int chunk = idx & 15;
        int r = idx >> 4;            // 0..3199
        int cell = r % 1600;
        int b = r / 1600;
        int pp;
        if (cell < 416)      pp = cell;                     // rows 0..3
        else if (cell < 832) pp = 100*PW2 + (cell - 416);   // rows 100..103
        else {
            int c2 = cell - 832;     // 0..767
            int row = 4 + (c2 >> 3); // 4..99
            int col = c2 & 7;        // 0..3 -> left, 4..7 -> right
            pp = row*PW2 + (col < 4 ? col : col + 96);
        }
        float* base = AT + (size_t)b*PN2 + (size_t)pp*CHN + chunk*4;
        *(float4*)base = make_float4(0.f, 0.f, 0.f, 0.f);
    }
}

// ---------------------------------------------------------------------------
// conv 9x9 (3 -> 64), pad 4, + PReLU. x window staged once in LDS.
// XCD-swizzled (y-slab per XCD, matches conv3's mapping).
__global__ __launch_bounds__(256) void k_conv_in(const float* __restrict__ x,
        const float* __restrict__ Win, const float* __restrict__ bias,
        const float* __restrict__ a, float* __restrict__ FR,
        short* __restrict__ FBI) {
    __shared__ float xw[3*9*40];     // [ci][ky][c], c = xs-(x0-4), 4320 B
    int t = threadIdx.x;
    int blk = blockIdx.x;
    int xcd = blk & 7;
    int l   = blk >> 3;              // 0..143 = b(2) x y%12(12) x s(6)
    int b  = l / 72;
    int r  = l % 72;
    int y  = xcd*12 + r/6;
    int s  = r % 6;                  // xc*2 + coh
    int xc  = s >> 1;
    int coh = s & 1;
    int x0 = xc*32;
    int px  = t & 31;
    int cog = t >> 5;                // 8 groups x 4 co (within this half)

    // ---- stage x window: rows y-4..y+4, cols x0-4..x0+35, 3 ci ----
    #pragma unroll
    for (int u = 0; u < 5; ++u) {
        int idx = u*256 + t;
        if (idx < 1080) {
            int ci = idx / 360;
            int rr = idx - ci*360;
            int ky = rr / 40;
            int c  = rr - ky*40;
            int yy = y + ky - 4;
            int xs = x0 + c - 4;
            float v = 0.f;
            if (yy >= 0 && yy < 96 && xs >= 0 && xs < 96)
                v = x[((size_t)(b*CIN + ci))*NSP + yy*96 + xs];
            xw[idx] = v;
        }
    }
    __syncthreads();

    int cbase = coh*32 + cog*4;
    float acc[4];
    #pragma unroll
    for (int rr = 0; rr < 4; ++rr) acc[rr] = bias[cbase + rr];

    #pragma unroll 1
    for (int ci = 0; ci < CIN; ++ci) {
        #pragma unroll 1
        for (int ky = 0; ky < 9; ++ky) {
            const float* xrow = xw + (ci*9 + ky)*40 + px;
            const float* wrow = Win + (size_t)(ci*81 + ky*9)*64 + cbase;
            float xv[9];
            #pragma unroll
            for (int kx = 0; kx < 9; ++kx) xv[kx] = xrow[kx];
            #pragma unroll
            for (int kx = 0; kx < 9; ++kx) {
                float4 wv = *(const float4*)(wrow + kx*64);
                acc[0] = fmaf(xv[kx], wv.x, acc[0]);
                acc[1] = fmaf(xv[kx], wv.y, acc[1]);
                acc[2] = fmaf(xv[kx], wv.z, acc[2]);
                acc[3] = fmaf(xv[kx], wv.w, acc[3]);
            }
        }
    }
    float sl = a[0];
    #pragma unroll
    for (int rr = 0; rr < 4; ++rr) {
        float v = acc[rr];
        acc[rr] = v >= 0.f ? v : sl*v;
    }
    int np = (y + 1)*PW + x0 + px + 1;
    float* fr = FR + ((size_t)b*PN + np)*CHN + cbase;
    *(float4*)fr = make_float4(acc[0], acc[1], acc[2], acc[3]);
    union { short ss[4]; short4 v4; } h4, l4;
    #pragma unroll
    for (int rr = 0; rr < 4; ++rr) split2(acc[rr], h4.ss[rr], l4.ss[rr]);
    short* fo = FBI + (size_t)b*FBST + (size_t)np*128 + cbase;
    *(short4*)fo        = h4.v4;
    *(short4*)(fo + 64) = l4.v4;
}

// ---------------------------------------------------------------------------
// 3x3 conv 64->64, implicit GEMM, split-bf16 3-MFMA, XCD-swizzled.
// Weight loads FRAGMENT-ORDER CONTIGUOUS (base + lane*16B = 1KB/inst).
// (r12 2-row variant failed the replay tripwire; this is the r11-verified
// single-row body, reverted verbatim.)
__global__ __launch_bounds__(256, 4) void k_conv3_mfma(
        const short* __restrict__ FBin,
        const short* __restrict__ Whi, const short* __restrict__ Wlo,
        const float* __restrict__ bias, const float* __restrict__ slope_p,
        float* __restrict__ FR, short* __restrict__ FBout, int mode) {
    __shared__ short xs[3*18*128];   // 13,824 B
    char* xb = (char*)xs;
    int t = threadIdx.x;
    int w = t >> 6, lane = t & 63;
    int q = lane >> 4, n16 = lane & 15;
    int blk = blockIdx.x;
    int xcd = blk & 7;
    int l   = blk >> 3;              // 0..143 = b(2) x y%12(12) x xchunk(6)
    int b   = l / 72;
    int rem = l % 72;
    int y   = xcd*12 + rem/6;
    int x0  = (rem % 6)*16;

    const short* fbB = FBin + (size_t)b*FBST;

    // ---- stage: 864 16-B granules, swizzled into LDS ----
    #pragma unroll
    for (int k = 0; k < 4; ++k) {
        int u = k*256 + t;
        if (u < 864) {
            int px_lin = u >> 4, G = u & 15;
            int r = px_lin / 18, p = px_lin - r*18;
            const float4 src = *(const float4*)(fbB
                + ((size_t)((y + r)*PW + x0 + p))*128 + G*8);
            *(float4*)(xb + (px_lin << 8) + ((G ^ (px_lin & 15)) << 4)) = src;
        }
    }
    __syncthreads();

    // ---- compute: wave = 16 px x 16 co (ct = w) ----
    int ct = w;
    f32x4 acc = {0,0,0,0};

    #pragma unroll
    for (int dy = 0; dy < 3; ++dy) {
        #pragma unroll
        for (int dx = 0; dx < 3; ++dx) {
            int kyx = dy*3 + dx;
            int px_lin = dy*18 + n16 + dx;
            int pbase = px_lin << 8;
            int sw = px_lin & 15;
            #pragma unroll
            for (int cih = 0; cih < 2; ++cih) {
                int Gh = cih*4 + q;
                int Gl = 8 + cih*4 + q;
                bf16x8 bhi = *(const bf16x8*)(xb + pbase + ((Gh ^ sw) << 4));
                bf16x8 blo = *(const bf16x8*)(xb + pbase + ((Gl ^ sw) << 4));
                size_t woff = ((size_t)((kyx*4 + ct)*2 + cih)*64 + lane)*8;
                bf16x8 ahi = *(const bf16x8*)(Whi + woff);
                bf16x8 alo = *(const bf16x8*)(Wlo + woff);
                acc = __builtin_amdgcn_mfma_f32_16x16x32_bf16(ahi, bhi, acc, 0, 0, 0);
                acc = __builtin_amdgcn_mfma_f32_16x16x32_bf16(ahi, blo, acc, 0, 0, 0);
                acc = __builtin_amdgcn_mfma_f32_16x16x32_bf16(alo, bhi, acc, 0, 0, 0);
            }
        }
    }

    // ---- epilogue: all outputs interior, vectorized stores ----
    int nb = (y + 1)*PW + x0 + 1 + n16;
    float sl = slope_p[0];
    short* fbo = FBout + (size_t)b*FBST + (size_t)nb*128;
    int co0 = ct*16 + q*4;
    float v[4];
    #pragma unroll
    for (int r = 0; r < 4; ++r) v[r] = acc[r] + bias[co0 + r];
    if (mode == 0) {
        #pragma unroll
        for (int r = 0; r < 4; ++r) v[r] = v[r] >= 0.f ? v[r] : sl*v[r];
    } else {
        float* fr = FR + ((size_t)b*PN + nb)*CHN + co0;
        float4 f = *(const float4*)fr;
        v[0] += f.x; v[1] += f.y; v[2] += f.z; v[3] += f.w;
        *(float4*)fr = make_float4(v[0], v[1], v[2], v[3]);
    }
    union { short s[4]; short4 v4; } h4, l4;
    #pragma unroll
    for (int r = 0; r < 4; ++r) split2(v[r], h4.s[r], l4.s[r]);
    *(short4*)(fbo + co0)      = h4.v4;
    *(short4*)(fbo + 64 + co0) = l4.v4;
}

// ---------------------------------------------------------------------------
// qkv projection as 1x1-conv implicit GEMM. N-space aligned blocks
// (coalesced V fragment stores). Weight loads fragment-order contiguous.
__global__ __launch_bounds__(256) void k_qkv_mfma(
        const short* __restrict__ FBin,
        const short* __restrict__ Wh, const short* __restrict__ Wl,
        const float* __restrict__ bq, const float* __restrict__ bk,
        const float* __restrict__ bv,
        short* __restrict__ Qb, short* __restrict__ Kb, short* __restrict__ Vb,
        float* __restrict__ Kinf) {
    __shared__ float kls[4][8];
    int t = threadIdx.x;
    int w = t >> 6, lane = t & 63;
    int q = lane >> 4, n16 = lane & 15;
    int blk = blockIdx.x;
    int b = blk / NCHK, chunk = blk % NCHK;
    int n  = chunk*64 + w*16 + n16;          // 0..9215, always valid
    int iy = n / WW, ix = n - iy*WW;
    int nb = (iy + 1)*PW + ix + 1;

    const short* fb = FBin + (size_t)b*FBST;
    f32x4 acc[5] = {{0,0,0,0},{0,0,0,0},{0,0,0,0},{0,0,0,0},{0,0,0,0}};

    int nbase = nb*128;
    #pragma unroll
    for (int cih = 0; cih < 2; ++cih) {
        bf16x8 bhi = *(const bf16x8*)(fb + nbase + cih*32 + q*8);
        bf16x8 blo = *(const bf16x8*)(fb + nbase + 64 + cih*32 + q*8);
        #pragma unroll
        for (int ct = 0; ct < 5; ++ct) {
            size_t aoff = ((size_t)(ct*2 + cih)*64 + lane)*8;
            bf16x8 ahi = *(const bf16x8*)(Wh + aoff);
            bf16x8 alo = *(const bf16x8*)(Wl + aoff);
            acc[ct] = __builtin_amdgcn_mfma_f32_16x16x32_bf16(ahi, bhi, acc[ct], 0, 0, 0);
            acc[ct] = __builtin_amdgcn_mfma_f32_16x16x32_bf16(ahi, blo, acc[ct], 0, 0, 0);
            acc[ct] = __builtin_amdgcn_mfma_f32_16x16x32_bf16(alo, bhi, acc[ct], 0, 0, 0);
        }
    }

    int jin = w*16 + n16;                    // j within chunk, wave-local
    float kabs[4] = {0.f, 0.f, 0.f, 0.f};
    union { short s[4]; short4 v4; } pk;
    if (q < 2) {
        #pragma unroll
        for (int r = 0; r < 4; ++r)
            pk.s[r] = f2b((acc[0][r] + bq[q*4 + r]) * LOG2E);
        *(short4*)(Qb + ((size_t)b*NSP + n)*8 + q*4) = pk.v4;
    } else {
        // K fragment coords (inverse of attn's jrow mapping)
        int ttk  = ((jin >> 5) << 1) | ((jin >> 2) & 1);
        int n16k = (((jin >> 3) & 3) << 2) | (jin & 3);
        size_t kbase = (((size_t)(b*NCHK + chunk)*4 + ttk)*16 + n16k)*8;
        #pragma unroll
        for (int r = 0; r < 4; ++r) {
            float kv = acc[0][r] + bk[(q - 2)*4 + r];
            kabs[r] = fabsf(kv) * 1.01f;
            pk.s[r] = f2b(kv);
        }
        *(short4*)(Kb + kbase + (q - 2)*4) = pk.v4;
    }
    // V fragment coords (j = ks*32 + quad*8 + e within chunk)
    int ksv = jin >> 5, qv = (jin >> 3) & 3, ev = jin & 7;
    size_t vbase = ((size_t)(b*NCHK + chunk)*2 + ksv)*2048 + qv*128 + ev;
    #pragma unroll
    for (int ct = 1; ct < 5; ++ct) {
        #pragma unroll
        for (int r = 0; r < 4; ++r) {
            int co = ct*16 + q*4 + r;
            Vb[vbase + (size_t)(ct - 1)*512 + (q*4 + r)*8] =
                f2b(acc[ct][r] + bv[co - 16]);
        }
    }
    #pragma unroll
    for (int r = 0; r < 4; ++r) {
        #pragma unroll
        for (int off = 1; off < 16; off <<= 1)
            kabs[r] = fmaxf(kabs[r], __shfl_xor(kabs[r], off));
    }
    if (q >= 2 && n16 == 0) {
        #pragma unroll
        for (int r = 0; r < 4; ++r)
            kls[w][(q - 2)*4 + r] = kabs[r];
    }
    __syncthreads();
    if (t < 8) {
        float m = fmaxf(fmaxf(kls[0][t], kls[1][t]),
                        fmaxf(kls[2][t], kls[3][t]));
        atomicMax((int*)&Kinf[t*KPAD], __float_as_int(m));
    }
}

// ---------------------------------------------------------------------------
// chunk buffer for attention (single-buffered: TLP beats ILP here — both
// the full dbuf (r2) and K-prefetch (r6) variants lost to occupancy).
struct CB { bf16x8 kf[4]; bf16x8 vf[8]; };

static __device__ __forceinline__ void attn_load(CB& cb,
        const short* __restrict__ KpJ, const short* __restrict__ VpJ,
        int n16, int lane) {
    #pragma unroll
    for (int tt = 0; tt < 4; ++tt)
        cb.kf[tt] = *(const bf16x8*)(KpJ + tt*128 + n16*8);
    #pragma unroll
    for (int ks = 0; ks < 2; ++ks)
        #pragma unroll
        for (int ct = 0; ct < 4; ++ct)
            cb.vf[ks*4 + ct] = *(const bf16x8*)(VpJ + (ks*4 + ct)*512 + lane*8);
}

static __device__ __forceinline__ void attn_compute(const CB& cb,
        const bf16x8 (&qf)[2], const f32x4 (&ci)[2],
        f32x4 (&accO)[2][4], float (&lp)[2]) {
    union PB { int di[8]; bf16x8 v8[2]; };
    PB pb[2];
    #pragma unroll
    for (int rg = 0; rg < 2; ++rg) {
        f32x4 e[4];
        #pragma unroll
        for (int tt = 0; tt < 4; ++tt)
            e[tt] = __builtin_amdgcn_mfma_f32_16x16x32_bf16(
                cb.kf[tt], qf[rg], ci[rg], 0, 0, 0);
        float st[4];
        #pragma unroll
        for (int tt = 0; tt < 4; ++tt) {
            #pragma unroll
            for (int r = 0; r < 4; ++r)
                e[tt][r] = __builtin_amdgcn_exp2f(e[tt][r]);
            st[tt] = (e[tt][0] + e[tt][1]) + (e[tt][2] + e[tt][3]);
        }
        lp[rg] += (st[0] + st[1]) + (st[2] + st[3]);
        // pack P to bf16 fragments eagerly (frees the 16 f32 e regs)
        #pragma unroll
        for (int tt = 0; tt < 4; ++tt) {
            pb[rg].di[tt*2]   = __builtin_amdgcn_perm(__float_as_uint(e[tt][1]),
                                             __float_as_uint(e[tt][0]), 0x07060302u);
            pb[rg].di[tt*2+1] = __builtin_amdgcn_perm(__float_as_uint(e[tt][3]),
                                             __float_as_uint(e[tt][2]), 0x07060302u);
        }
    }
    #pragma unroll
    for (int ks = 0; ks < 2; ++ks)
        #pragma unroll
        for (int rg = 0; rg < 2; ++rg)
            #pragma unroll
            for (int ct = 0; ct < 4; ++ct)
                accO[rg][ct] = __builtin_amdgcn_mfma_f32_16x16x32_bf16(
                    pb[rg].v8[ks], cb.vf[ks*4 + ct], accO[rg][ct], 0, 0, 0);
}

// MFMA flash attention, bound-based softmax, j split across 4 blocks.
__global__ __launch_bounds__(256) void k_attn_mfma(
        const short* __restrict__ Qb, const short* __restrict__ Kb,
        const short* __restrict__ Vb, const float* __restrict__ Kinf_p,
        float* __restrict__ Opg, float* __restrict__ lg) {
    __shared__ float Opart[4][16][68];
    __shared__ float lsh[4][2][16];

    int blk = blockIdx.x;
    int b    = blk / (NRB*NQTR);
    int rem  = blk % (NRB*NQTR);
    int rb   = rem / NQTR;
    int qtr  = rem % NQTR;
    int i0 = rb*32;
    int t = threadIdx.x;
    int w = t >> 6;
    int lane = t & 63;
    int quad = lane >> 4, n16 = lane & 15;

    const short* Qp = Qb + ((size_t)b*NSP)*8;
    const short* Kp = Kb + ((size_t)b*NSP)*8;
    const short* Vp = Vb + ((size_t)b*CHN)*NSP;

    bf16x8 qf[2];
    float Mi[2];
    #pragma unroll
    for (int rg = 0; rg < 2; ++rg) {
        bf16x8 z = {0,0,0,0,0,0,0,0};
        qf[rg] = z;
        if (quad == 0)
            qf[rg] = *(const bf16x8*)(Qp + (size_t)(i0 + rg*16 + n16)*8);
        float s1 = 0.f;
        #pragma unroll
        for (int c = 0; c < 8; ++c)
            s1 += fabsf(b2f(qf[rg][c])) * Kinf_p[c*KPAD];
        float Mv = s1 + 1.0f - BOOST;
        Mi[rg] = __shfl(Mv, n16);
    }

    f32x4 accO[2][4] = {{{0,0,0,0},{0,0,0,0},{0,0,0,0},{0,0,0,0}},
                        {{0,0,0,0},{0,0,0,0},{0,0,0,0},{0,0,0,0}}};
    float lp[2] = {0.f, 0.f};
    f32x4 ci[2];
    #pragma unroll
    for (int rg = 0; rg < 2; ++rg) {
        ci[rg][0] = -Mi[rg]; ci[rg][1] = -Mi[rg];
        ci[rg][2] = -Mi[rg]; ci[rg][3] = -Mi[rg];
    }

    // wave w covers 9 chunks of 64 j within its quarter
    int Jb = qtr*36 + w*9;
    const short* KpJ = Kp + (size_t)Jb*512;
    const short* VpJ = Vp + (size_t)Jb*4096;

    #pragma unroll 1
    for (int jc = 0; jc < 9; ++jc) {
        CB cb;
        attn_load(cb, KpJ, VpJ, n16, lane);
        attn_compute(cb, qf, ci, accO, lp);
        KpJ += 512;
        VpJ += 4096;
    }

    // ---- epilogue: cross-wave reduce, rg-looped to halve LDS ----
    #pragma unroll
    for (int rg = 0; rg < 2; ++rg) {
        float l = lp[rg];
        l += __shfl_xor(l, 16);
        l += __shfl_xor(l, 32);
        if (quad == 0) lsh[w][rg][n16] = l;
    }

    size_t obase = (((size_t)(b*NRB + rb))*NQTR + qtr)*2048;
    int row16 = t >> 4;          // 0..15
    int c0 = (t & 15)*4;
    #pragma unroll
    for (int rg = 0; rg < 2; ++rg) {
        if (rg) __syncthreads();
        #pragma unroll
        for (int ct = 0; ct < 4; ++ct)
            #pragma unroll
            for (int r = 0; r < 4; ++r)
                Opart[w][quad*4 + r][ct*16 + n16] = accO[rg][ct][r];
        __syncthreads();
        #pragma unroll
        for (int cc = 0; cc < 4; ++cc) {
            int c = c0 + cc;
            Opg[obase + (size_t)(rg*16 + row16)*64 + c] =
                Opart[0][row16][c] + Opart[1][row16][c]
              + Opart[2][row16][c] + Opart[3][row16][c];
        }
    }
    if (t < 32) {
        int rgl = t >> 4, ii = t & 15;
        lg[(((size_t)(b*NRB + rb))*NQTR + qtr)*32 + t] =
            lsh[0][rgl][ii] + lsh[1][rgl][ii]
          + lsh[2][rgl][ii] + lsh[3][rgl][ii];
    }
}

// ---------------------------------------------------------------------------
// attention finalize: merge j-quarters, normalize, add residual, write AT.
__global__ __launch_bounds__(256) void k_attn_fin(
        const float* __restrict__ Opg, const float* __restrict__ lg,
        const float* __restrict__ FR, const float* __restrict__ gamma_p,
        float* __restrict__ AT) {
    int blk = blockIdx.x;            // b*NRB + rb
    int b = blk / NRB, rb = blk % NRB;
    int t = threadIdx.x;
    int row = t >> 3;
    int c0 = (t & 7)*8;
    float g = gamma_p[0];
    size_t ob = ((size_t)blk*NQTR)*2048 + (size_t)row*64;
    float l = 0.f;
    #pragma unroll
    for (int k = 0; k < NQTR; ++k)
        l += lg[((size_t)blk*NQTR + k)*32 + row];
    float inv = g / fmaxf(l, 1e-35f);
    int gi = rb*32 + row;
    int iy = gi / WW, ix = gi - iy*WW;
    size_t frb = ((size_t)b*PN + (iy + 1)*PW + ix + 1)*CHN;
    size_t atb = ((size_t)b*PN2 + (iy + 4)*PW2 + ix + 4)*CHN;
    #pragma unroll
    for (int cc = 0; cc < 8; ++cc) {
        int c = c0 + cc;
        float Ov = 0.f;
        #pragma unroll
        for (int k = 0; k < NQTR; ++k)
            Ov += Opg[ob + (size_t)k*2048 + c];
        AT[atb + c] = Ov*inv + FR[frb + c];
    }
}

// ---------------------------------------------------------------------------
// conv 9x9 (64 -> 3) + tanh. Wave per 4 pixels, lane = ci.
__global__ __launch_bounds__(256) void k_conv_out(const float* __restrict__ AT,
        const float* __restrict__ Wo, const float* __restrict__ bias,
        float* __restrict__ out) {
    int t = threadIdx.x;
    int w = t >> 6, lane = t & 63;
    int base = blockIdx.x*16 + w*4;
    int b = base / NSP;
    int n0 = base % NSP;
    int y0 = n0 / WW, x0 = n0 % WW;

    float s[4][3] = {{0,0,0},{0,0,0},{0,0,0},{0,0,0}};
    for (int ky = 0; ky < 9; ++ky) {
        const float* arow = AT + ((size_t)b*PN2 + (size_t)(y0 + ky)*PW2 + x0)*CHN + lane;
        const float* wrow = Wo + (size_t)ky*9*192;
        float xv[12];
        #pragma unroll
        for (int u = 0; u < 12; ++u)
            xv[u] = arow[(size_t)u*CHN];
        #pragma unroll
        for (int kx = 0; kx < 9; ++kx) {
            float w0 = wrow[kx*192 +   0 + lane];
            float w1 = wrow[kx*192 +  64 + lane];
            float w2 = wrow[kx*192 + 128 + lane];
            #pragma unroll
            for (int p = 0; p < 4; ++p) {
                float x = xv[kx + p];
                s[p][0] = fmaf(x, w0, s[p][0]);
                s[p][1] = fmaf(x, w1, s[p][1]);
                s[p][2] = fmaf(x, w2, s[p][2]);
            }
        }
    }
    #pragma unroll
    for (int p = 0; p < 4; ++p)
        #pragma unroll
        for (int c = 0; c < 3; ++c) {
            float v = s[p][c];
            v += __shfl_xor(v, 1);
            v += __shfl_xor(v, 2);
            v += __shfl_xor(v, 4);
            v += __shfl_xor(v, 8);
            v += __shfl_xor(v, 16);
            v += __shfl_xor(v, 32);
            s[p][c] = v;
        }
    #pragma unroll
    for (int p = 0; p < 4; ++p)
        #pragma unroll
        for (int c = 0; c < 3; ++c)
            if (lane == p*3 + c)
                out[((size_t)(b*3 + c))*NSP + n0 + p] = tanhf(s[p][c] + bias[c]);
}

// ---------------------------------------------------------------------------
extern "C" void kernel_launch(void* const* d_in, const int* in_sizes, int n_in,
                              void* d_out, int out_size, void* d_ws, size_t ws_size,
                              hipStream_t stream) {
    (void)in_sizes; (void)n_in; (void)out_size; (void)ws_size;
    const float* x     = (const float*)d_in[0];
    const float* w_in  = (const float*)d_in[1];
    const float* b_in  = (const float*)d_in[2];
    const float* a_in  = (const float*)d_in[3];
    const float* rw1   = (const float*)d_in[4];
    const float* rb1   = (const float*)d_in[5];
    const float* ra    = (const float*)d_in[6];
    const float* rw2   = (const float*)d_in[7];
    const float* rb2   = (const float*)d_in[8];
    const float* wq    = (const float*)d_in[9];
    const float* bq    = (const float*)d_in[10];
    const float* wk    = (const float*)d_in[11];
    const float* bk    = (const float*)d_in[12];
    const float* wv    = (const float*)d_in[13];
    const float* bv    = (const float*)d_in[14];
    const float* gamma = (const float*)d_in[15];
    const float* w_out = (const float*)d_in[16];
    const float* b_out = (const float*)d_in[17];

    const size_t SZ_FR  = (size_t)BATCH*PN*CHN*4;        // 4,917,248
    const size_t SZ_FBI = (size_t)BATCH*FBST*2;          // 5,048,320
    const size_t SZ_WT  = (size_t)NBLK*2*9*CHN*CHN*2;    //   737,280
    const size_t SZ_QK  = (size_t)BATCH*NSP*C8*2;        //   294,912
    const size_t SZ_VB  = (size_t)BATCH*CHN*NSP*2;       // 2,359,296
    const size_t SZ_AT  = (size_t)BATCH*PN2*CHN*4;       // 5,537,792
    const size_t SZ_WO  = (size_t)81*CIN*CHN*4;          //    62,208
    const size_t SZ_WIN = (size_t)243*CHN*4;             //    62,208
    const size_t SZ_WQ  = (size_t)80*CHN*2;              //    10,240
    const size_t SZ_OP  = (size_t)BATCH*NRB*NQTR*2048*4; // 18,874,368
    const size_t SZ_LG  = (size_t)BATCH*NRB*NQTR*32*4;   //   294,912
    const size_t SZ_KI  = (size_t)8*KPAD*4;              //       512
    char* p = (char*)d_ws;
    float* FR      = (float*)p;           p += SZ_FR;
    short* FBI0raw = (short*)p;           p += SZ_FBI;
    short* FBI1raw = (short*)p;           p += SZ_FBI;
    short* Whi     = (short*)p;           p += SZ_WT;
    short* Wlo     = (short*)p;           p += SZ_WT;
    short* Qb16    = (short*)p;           p += SZ_QK;
    short* Kb16    = (short*)p;           p += SZ_QK;
    short* Vb16    = (short*)p;           p += SZ_VB;
    float* AT      = (float*)p;           p += SZ_AT;
    float* Wo      = (float*)p;           p += SZ_WO;
    float* Win     = (float*)p;           p += SZ_WIN;
    short* Wqh     = (short*)p;           p += SZ_WQ;
    short* Wql     = (short*)p;           p += SZ_WQ;
    float* Opg     = (float*)p;           p += SZ_OP;
    float* lgb     = (float*)p;           p += SZ_LG;
    float* Kinf    = (float*)p;           p += SZ_KI;
    short* FBI0 = FBI0raw + (size_t)GUARD*128;
    short* FBI1 = FBI1raw + (size_t)GUARD*128;
    float* outp = (float*)d_out;

    hipMemsetAsync(Kinf, 0, SZ_KI, stream);

    dim3 blk(256);

    // prep + border-zero fused (one launch; ranges independent)
    const int PREP_TOT = NBLK*2*9*CHN*CHN + 80*CHN + 81*CIN*CHN + 243*CHN
                       + 2*2*388*16 + 2*1600*16;   // 480,896
    k_prep_all<<<(PREP_TOT + 255)/256, blk, 0, stream>>>(
        rw1, rw2, Whi, Wlo, wq, wk, wv, Wqh, Wql, w_out, Wo, w_in, Win,
        FBI0, FBI1, AT);
    k_conv_in<<<BATCH*96*3*2, blk, 0, stream>>>(x, Win, b_in, a_in, FR, FBI0);
    for (int i = 0; i < NBLK; ++i) {
        k_conv3_mfma<<<BATCH*576, blk, 0, stream>>>(
            FBI0,
            Whi + (size_t)(2*i)*9*CHN*CHN, Wlo + (size_t)(2*i)*9*CHN*CHN,
            rb1 + i*CHN, ra + i, (float*)nullptr, FBI1, 0);
        k_conv3_mfma<<<BATCH*576, blk, 0, stream>>>(
            FBI1,
            Whi + (size_t)(2*i+1)*9*CHN*CHN, Wlo + (size_t)(2*i+1)*9*CHN*CHN,
            rb2 + i*CHN, ra + i, FR, FBI0, 1);
    }
    k_qkv_mfma<<<BATCH*NCHK, blk, 0, stream>>>(
        FBI0, Wqh, Wql, bq, bk, bv, Qb16, Kb16, Vb16, Kinf);
    k_attn_mfma<<<BATCH*NRB*NQTR, blk, 0, stream>>>(
        Qb16, Kb16, Vb16, Kinf, Opg, lgb);
    k_attn_fin<<<BATCH*NRB, blk, 0, stream>>>(Opg, lgb, FR, gamma, AT);
    k_conv_out<<<(BATCH*NSP)/16, blk, 0, stream>>>(AT, Wo, b_out, outp);
}